// Round 1
// baseline (924.961 us; speedup 1.0000x reference)
//
#include <hip/hip_runtime.h>

typedef unsigned short u16;
typedef unsigned int u32;

typedef __bf16 bf16x8 __attribute__((ext_vector_type(8)));
typedef float f32x4 __attribute__((ext_vector_type(4)));

#define TSEQ 4096
#define DDIM 1024
#define NB 4
#define EPSV 1e-6f

__device__ __forceinline__ u16 f2b(float f) {
    union { float f; u32 u; } v; v.f = f;
    u32 r = v.u + 0x7FFFu + ((v.u >> 16) & 1u);
    return (u16)(r >> 16);
}
__device__ __forceinline__ float b2f(u16 h) {
    union { u32 u; float f; } v; v.u = ((u32)h) << 16; return v.f;
}

// ---------------- conversion kernels ----------------
__global__ void k_conv_x(const float* __restrict__ x, u16* __restrict__ xw) {
    size_t i = ((size_t)blockIdx.x * 256 + threadIdx.x) * 4;
    float4 f = *(const float4*)(x + i);
    ushort4 u;
    u.x = f2b(f.x); u.y = f2b(f.y); u.z = f2b(f.z); u.w = f2b(f.w);
    *(ushort4*)(xw + i) = u;
}

__global__ void k_conv_w(const float* __restrict__ wq, const float* __restrict__ wk,
                         const float* __restrict__ wv, const float* __restrict__ wa,
                         u16* __restrict__ wcat) {
    size_t i = ((size_t)blockIdx.x * 256 + threadIdx.x) * 4;
    int sel = (int)(i >> 20);
    const float* src = (sel == 0) ? wq : (sel == 1) ? wk : (sel == 2) ? wv : wa;
    size_t loc = i & ((1u << 20) - 1);
    float4 f = *(const float4*)(src + loc);
    ushort4 u;
    u.x = f2b(f.x); u.y = f2b(f.y); u.z = f2b(f.z); u.w = f2b(f.w);
    *(ushort4*)(wcat + i) = u;
}

__global__ void k_conv_b(const float* __restrict__ bq, const float* __restrict__ bk,
                         const float* __restrict__ bv, const float* __restrict__ ba,
                         float* __restrict__ bcat) {
    int j = blockIdx.x * 256 + threadIdx.x;  // 0..4095
    int sel = j >> 10;
    const float* src = (sel == 0) ? bq : (sel == 1) ? bk : (sel == 2) ? bv : ba;
    bcat[j] = src[j & 1023];
}

// ---------------- GEMM core helpers ----------------
// Stage a 128-row x 64-col bf16 tile (row-major, row stride ld elements) into LDS.
__device__ __forceinline__ void stage_tile(u16* __restrict__ dst, const u16* __restrict__ src,
                                           int row0, int k0, int ld, int tid) {
#pragma unroll
    for (int p = 0; p < 4; ++p) {
        int off = p * 4096 + tid * 16;  // byte offset within 16KB tile
        int r = off >> 7;               // tile row (128 B per row)
        int cb = off & 127;             // byte within row
        const char* g = (const char*)src + ((size_t)(row0 + r) * ld + k0) * 2 + cb;
        *(uint4*)((char*)dst + off) = *(const uint4*)g;
    }
}

// One BK=64 step of MFMA on staged tiles. Wave computes 64x64 (4x4 of 16x16x32).
__device__ __forceinline__ void mma_tile(const u16* __restrict__ As, const u16* __restrict__ Bs,
                                         f32x4 acc[4][4], int wm, int wn, int quad, int l15) {
#pragma unroll
    for (int kk = 0; kk < 64; kk += 32) {
        bf16x8 a[4], b[4];
#pragma unroll
        for (int i = 0; i < 4; ++i) {
            a[i] = *(const bf16x8*)(As + (wm * 64 + i * 16 + l15) * 64 + kk + quad * 8);
            b[i] = *(const bf16x8*)(Bs + (wn * 64 + i * 16 + l15) * 64 + kk + quad * 8);
        }
#pragma unroll
        for (int i = 0; i < 4; ++i)
#pragma unroll
            for (int j = 0; j < 4; ++j)
                acc[i][j] = __builtin_amdgcn_mfma_f32_16x16x32_bf16(a[i], b[j], acc[i][j], 0, 0, 0);
    }
}

// ---------------- fused QKVA projection GEMM ----------------
// C[m,n] = sum_k x[m,k] * Wcat[n,k]; epilogue splits n into q/k/v/A outputs.
__global__ __launch_bounds__(256) void k_gemm_qkva(
    const u16* __restrict__ xw, const u16* __restrict__ wcat, const float* __restrict__ bcat,
    u16* __restrict__ qb, u16* __restrict__ kb, u16* __restrict__ vb, float* __restrict__ gA) {
    __shared__ u16 As[128 * 64];
    __shared__ u16 Bs[128 * 64];
    int tid = threadIdx.x;
    int m0 = blockIdx.y * 128, n0 = blockIdx.x * 128;
    int wid = tid >> 6, lane = tid & 63;
    int wm = wid >> 1, wn = wid & 1, quad = lane >> 4, l15 = lane & 15;
    f32x4 acc[4][4] = {};
    for (int k0 = 0; k0 < DDIM; k0 += 64) {
        stage_tile(As, xw, m0, k0, DDIM, tid);
        stage_tile(Bs, wcat, n0, k0, DDIM, tid);
        __syncthreads();
        mma_tile(As, Bs, acc, wm, wn, quad, l15);
        __syncthreads();
    }
#pragma unroll
    for (int im = 0; im < 4; ++im) {
#pragma unroll
        for (int jn = 0; jn < 4; ++jn) {
            int n = n0 + wn * 64 + jn * 16 + l15;
            float bias = bcat[n];
            int blk = n >> 10, nf = n & 1023;
#pragma unroll
            for (int r = 0; r < 4; ++r) {
                int m = m0 + wm * 64 + im * 16 + quad * 4 + r;
                float z = acc[im][jn][r] + bias;
                size_t o = (size_t)m * DDIM + nf;
                if (blk == 0)      qb[o] = f2b(fmaxf(z, 0.f));
                else if (blk == 1) kb[o] = f2b(fmaxf(z, 0.f));
                else if (blk == 2) vb[o] = f2b(z);
                else               gA[o] = logf(1.f / (1.f + expf(-z)) + 1e-6f);
            }
        }
    }
}

// ---------------- transpose v -> vT [B][D][T] ----------------
__global__ void k_transpose_v(const u16* __restrict__ v, u16* __restrict__ vT) {
    __shared__ u16 tile[64][65];
    int b = blockIdx.z, s0 = blockIdx.x * 64, j0 = blockIdx.y * 64;
    int tx = threadIdx.x & 63, ty = threadIdx.x >> 6;
#pragma unroll
    for (int r = ty; r < 64; r += 4)
        tile[r][tx] = v[((size_t)(b * TSEQ + s0 + r) << 10) + j0 + tx];
    __syncthreads();
#pragma unroll
    for (int r = ty; r < 64; r += 4)
        vT[((size_t)(b * DDIM + j0 + r) << 12) + s0 + tx] = tile[tx][r];
}

// ---------------- gate scan (3 passes, chunks of 64 rows) ----------------
__global__ void k_scan_part(const float* __restrict__ gA, float* __restrict__ part) {
    int c = blockIdx.x, b = blockIdx.y, tid = threadIdx.x;
    float a0 = 0, a1 = 0, a2 = 0, a3 = 0;
    size_t base = ((size_t)(b * TSEQ + c * 64)) << 10;
    for (int s = 0; s < 64; ++s) {
        const float* row = gA + base + ((size_t)s << 10);
        a0 += row[tid]; a1 += row[tid + 256]; a2 += row[tid + 512]; a3 += row[tid + 768];
    }
    float* p = part + ((size_t)(b * 64 + c) << 10);
    p[tid] = a0; p[tid + 256] = a1; p[tid + 512] = a2; p[tid + 768] = a3;
}

__global__ __launch_bounds__(1024) void k_scan_sweep(float* __restrict__ part) {
    int b = blockIdx.x, tid = threadIdx.x;  // 1024 threads
    float run = 0;
    for (int c = 63; c >= 0; --c) {
        float* p = part + ((size_t)(b * 64 + c) << 10) + tid;
        float val = *p; *p = run; run += val;
    }
}

__global__ void k_scan_apply(const float* __restrict__ gA, const float* __restrict__ part,
                             u16* __restrict__ kb) {
    int c = blockIdx.x, b = blockIdx.y, tid = threadIdx.x;
    const float* p = part + ((size_t)(b * 64 + c) << 10);
    float r0 = p[tid], r1 = p[tid + 256], r2 = p[tid + 512], r3 = p[tid + 768];
    size_t base = ((size_t)(b * TSEQ + c * 64)) << 10;
    for (int s = 63; s >= 0; --s) {
        size_t ro = base + ((size_t)s << 10);
        r0 += gA[ro + tid];
        kb[ro + tid] = f2b(b2f(kb[ro + tid]) * expf(r0));
        r1 += gA[ro + tid + 256];
        kb[ro + tid + 256] = f2b(b2f(kb[ro + tid + 256]) * expf(r1));
        r2 += gA[ro + tid + 512];
        kb[ro + tid + 512] = f2b(b2f(kb[ro + tid + 512]) * expf(r2));
        r3 += gA[ro + tid + 768];
        kb[ro + tid + 768] = f2b(b2f(kb[ro + tid + 768]) * expf(r3));
    }
}

// ---------------- scores = q @ wk^T (causal), bf16 out + denom atomics ----------------
__global__ __launch_bounds__(256) void k_scores(
    const u16* __restrict__ qb, const u16* __restrict__ wkb,
    u16* __restrict__ scores, float* __restrict__ denom) {
    int si = blockIdx.x, ti = blockIdx.y, b = blockIdx.z;
    if (si > ti) return;
    __shared__ u16 As[128 * 64];
    __shared__ u16 Bs[128 * 64];
    int tid = threadIdx.x;
    const u16* A = qb + ((size_t)b << 22);
    const u16* Bm = wkb + ((size_t)b << 22);
    int t0 = ti * 128, s0 = si * 128;
    int wid = tid >> 6, lane = tid & 63;
    int wm = wid >> 1, wn = wid & 1, quad = lane >> 4, l15 = lane & 15;
    f32x4 acc[4][4] = {};
    for (int k0 = 0; k0 < DDIM; k0 += 64) {
        stage_tile(As, A, t0, k0, DDIM, tid);
        stage_tile(Bs, Bm, s0, k0, DDIM, tid);
        __syncthreads();
        mma_tile(As, Bs, acc, wm, wn, quad, l15);
        __syncthreads();
    }
#pragma unroll
    for (int im = 0; im < 4; ++im) {
#pragma unroll
        for (int r = 0; r < 4; ++r) {
            int trow = t0 + wm * 64 + im * 16 + quad * 4 + r;
            float rs = 0.f;
#pragma unroll
            for (int jn = 0; jn < 4; ++jn) {
                int s = s0 + wn * 64 + jn * 16 + l15;
                float val = acc[im][jn][r];
                if (s > trow) val = 0.f;
                rs += val;
                scores[((size_t)(b * TSEQ + trow) << 12) + s] = f2b(val);
            }
#pragma unroll
            for (int m = 1; m < 16; m <<= 1) rs += __shfl_xor(rs, m, 64);
            if (l15 == 0) atomicAdd(denom + (b << 12) + trow, rs);
        }
    }
}

// ---------------- num = scores @ v (causal K bound), divide by denom ----------------
__global__ __launch_bounds__(256) void k_num(
    const u16* __restrict__ scores, const u16* __restrict__ vT,
    const float* __restrict__ denom, float* __restrict__ out) {
    int ji = blockIdx.x, ti = blockIdx.y, b = blockIdx.z;
    __shared__ u16 As[128 * 64];
    __shared__ u16 Bs[128 * 64];
    int tid = threadIdx.x;
    const u16* A = scores + ((size_t)b << 24);  // [T][T]
    const u16* Bm = vT + ((size_t)b << 22);     // [D][T]
    int t0 = ti * 128, j0 = ji * 128;
    int wid = tid >> 6, lane = tid & 63;
    int wm = wid >> 1, wn = wid & 1, quad = lane >> 4, l15 = lane & 15;
    f32x4 acc[4][4] = {};
    int kmax = (ti + 1) * 128;
    for (int k0 = 0; k0 < kmax; k0 += 64) {
        stage_tile(As, A, t0, k0, TSEQ, tid);
        stage_tile(Bs, Bm, j0, k0, TSEQ, tid);
        __syncthreads();
        mma_tile(As, Bs, acc, wm, wn, quad, l15);
        __syncthreads();
    }
#pragma unroll
    for (int im = 0; im < 4; ++im) {
#pragma unroll
        for (int r = 0; r < 4; ++r) {
            int t = t0 + wm * 64 + im * 16 + quad * 4 + r;
            float den = denom[(b << 12) + t] + EPSV;
#pragma unroll
            for (int jn = 0; jn < 4; ++jn) {
                int j = j0 + wn * 64 + jn * 16 + l15;
                out[((size_t)(b * TSEQ + t) << 10) + j] = acc[im][jn][r] / den;
            }
        }
    }
}

// ---------------- workspace layout (bytes) ----------------
// persistent: q | wk | vT | denom | bcat
// early (overlaid by scores later): xw | wcat | v | gA | part
static const size_t OFF_Q      = 0;
static const size_t OFF_WK     = 33554432;
static const size_t OFF_VT     = 67108864;
static const size_t OFF_DENOM  = 100663296;
static const size_t OFF_BCAT   = 100728832;
static const size_t OFF_XW     = 100745216;
static const size_t OFF_WCAT   = 134299648;
static const size_t OFF_V      = 142688256;
static const size_t OFF_GA     = 176242688;
static const size_t OFF_PART   = 243351552;
static const size_t OFF_SCORES = OFF_XW;  // 134,217,728 B, overlays dead early region

extern "C" void kernel_launch(void* const* d_in, const int* in_sizes, int n_in,
                              void* d_out, int out_size, void* d_ws, size_t ws_size,
                              hipStream_t stream) {
    const float* x  = (const float*)d_in[0];
    const float* Wq = (const float*)d_in[1];
    const float* bq = (const float*)d_in[2];
    const float* Wk = (const float*)d_in[3];
    const float* bk = (const float*)d_in[4];
    const float* Wv = (const float*)d_in[5];
    const float* bv = (const float*)d_in[6];
    const float* Wa = (const float*)d_in[7];
    const float* ba = (const float*)d_in[8];
    float* out = (float*)d_out;

    char* W = (char*)d_ws;
    u16* qb      = (u16*)(W + OFF_Q);
    u16* wkb     = (u16*)(W + OFF_WK);
    u16* vT      = (u16*)(W + OFF_VT);
    float* denom = (float*)(W + OFF_DENOM);
    float* bcat  = (float*)(W + OFF_BCAT);
    u16* xw      = (u16*)(W + OFF_XW);
    u16* wcat    = (u16*)(W + OFF_WCAT);
    u16* vb      = (u16*)(W + OFF_V);
    float* gA    = (float*)(W + OFF_GA);
    float* part  = (float*)(W + OFF_PART);
    u16* scores  = (u16*)(W + OFF_SCORES);

    hipMemsetAsync(denom, 0, (size_t)NB * TSEQ * sizeof(float), stream);

    k_conv_x<<<16384, 256, 0, stream>>>(x, xw);
    k_conv_w<<<4096, 256, 0, stream>>>(Wq, Wk, Wv, Wa, wcat);
    k_conv_b<<<16, 256, 0, stream>>>(bq, bk, bv, ba, bcat);

    k_gemm_qkva<<<dim3(32, 128), 256, 0, stream>>>(xw, wcat, bcat, qb, wkb, vb, gA);

    k_transpose_v<<<dim3(64, 16, NB), 256, 0, stream>>>(vb, vT);

    k_scan_part<<<dim3(64, NB), 256, 0, stream>>>(gA, part);
    k_scan_sweep<<<NB, 1024, 0, stream>>>(part);
    k_scan_apply<<<dim3(64, NB), 256, 0, stream>>>(gA, part, wkb);

    k_scores<<<dim3(32, 32, NB), 256, 0, stream>>>(qb, wkb, scores, denom);

    k_num<<<dim3(8, 32, NB), 256, 0, stream>>>(scores, vT, denom, out);
}

// Round 2
// 885.437 us; speedup vs baseline: 1.0446x; 1.0446x over previous
//
#include <hip/hip_runtime.h>

typedef unsigned short u16;
typedef unsigned int u32;

typedef __bf16 bf16x8 __attribute__((ext_vector_type(8)));
typedef float f32x4 __attribute__((ext_vector_type(4)));

#define TSEQ 4096
#define DDIM 1024
#define NB 4
#define EPSV 1e-6f

__device__ __forceinline__ u16 f2b(float f) {
    union { float f; u32 u; } v; v.f = f;
    u32 r = v.u + 0x7FFFu + ((v.u >> 16) & 1u);
    return (u16)(r >> 16);
}
__device__ __forceinline__ float b2f(u16 h) {
    union { u32 u; float f; } v; v.u = ((u32)h) << 16; return v.f;
}

// ---------------- conversion kernels ----------------
__global__ void k_conv_x(const float* __restrict__ x, u16* __restrict__ xw) {
    size_t i = ((size_t)blockIdx.x * 256 + threadIdx.x) * 4;
    float4 f = *(const float4*)(x + i);
    ushort4 u;
    u.x = f2b(f.x); u.y = f2b(f.y); u.z = f2b(f.z); u.w = f2b(f.w);
    *(ushort4*)(xw + i) = u;
}

__global__ void k_conv_w(const float* __restrict__ wq, const float* __restrict__ wk,
                         const float* __restrict__ wv, const float* __restrict__ wa,
                         u16* __restrict__ wcat) {
    size_t i = ((size_t)blockIdx.x * 256 + threadIdx.x) * 4;
    int sel = (int)(i >> 20);
    const float* src = (sel == 0) ? wq : (sel == 1) ? wk : (sel == 2) ? wv : wa;
    size_t loc = i & ((1u << 20) - 1);
    float4 f = *(const float4*)(src + loc);
    ushort4 u;
    u.x = f2b(f.x); u.y = f2b(f.y); u.z = f2b(f.z); u.w = f2b(f.w);
    *(ushort4*)(wcat + i) = u;
}

__global__ void k_conv_b(const float* __restrict__ bq, const float* __restrict__ bk,
                         const float* __restrict__ bv, const float* __restrict__ ba,
                         float* __restrict__ bcat) {
    int j = blockIdx.x * 256 + threadIdx.x;  // 0..4095
    int sel = j >> 10;
    const float* src = (sel == 0) ? bq : (sel == 1) ? bk : (sel == 2) ? bv : ba;
    bcat[j] = src[j & 1023];
}

// ---------------- GEMM core helpers ----------------
// Async-stage a 128-row x 64-col bf16 tile (row-major, stride ld elements) into LDS.
// Wave wid stages rows [wid*32, wid*32+32) as 4 chunks of 8 rows (1 KB each).
// LDS dest is wave-uniform chunk base + lane*16 (global_load_lds constraint);
// lane l loads row chunk+l/8, bytes (l%8)*16 -> lands at exactly base+l*16.
__device__ __forceinline__ void stage_async(u16* __restrict__ dst, const u16* __restrict__ src,
                                            int row0, int k0, int ld, int wid, int lane) {
#pragma unroll
    for (int c = 0; c < 4; ++c) {
        int rbase = wid * 32 + c * 8;
        int r = rbase + (lane >> 3);
        int cb = (lane & 7) * 16;
        const char* g = (const char*)src + ((size_t)(row0 + r) * ld + k0) * 2 + cb;
        char* l = (char*)dst + rbase * 128 + lane * 16;
        __builtin_amdgcn_global_load_lds((const __attribute__((address_space(1))) u32*)g,
                                         (__attribute__((address_space(3))) u32*)l, 16, 0, 0);
    }
}

// One BK=64 step of MFMA on staged tiles. Wave computes 64x64 (4x4 of 16x16x32).
__device__ __forceinline__ void mma_tile(const u16* __restrict__ As, const u16* __restrict__ Bs,
                                         f32x4 acc[4][4], int wm, int wn, int quad, int l15) {
#pragma unroll
    for (int kk = 0; kk < 64; kk += 32) {
        bf16x8 a[4], b[4];
#pragma unroll
        for (int i = 0; i < 4; ++i) {
            a[i] = *(const bf16x8*)(As + (wm * 64 + i * 16 + l15) * 64 + kk + quad * 8);
            b[i] = *(const bf16x8*)(Bs + (wn * 64 + i * 16 + l15) * 64 + kk + quad * 8);
        }
#pragma unroll
        for (int i = 0; i < 4; ++i)
#pragma unroll
            for (int j = 0; j < 4; ++j)
                acc[i][j] = __builtin_amdgcn_mfma_f32_16x16x32_bf16(a[i], b[j], acc[i][j], 0, 0, 0);
    }
}

// ---------------- fused QKVA projection GEMM ----------------
// C[m,n] = sum_k x[m,k] * Wcat[n,k]; epilogue splits n into q/k/v/A outputs.
__global__ __launch_bounds__(256) void k_gemm_qkva(
    const u16* __restrict__ xw, const u16* __restrict__ wcat, const float* __restrict__ bcat,
    u16* __restrict__ qb, u16* __restrict__ kb, u16* __restrict__ vb, float* __restrict__ gA) {
    __shared__ u16 As[128 * 64];
    __shared__ u16 Bs[128 * 64];
    int tid = threadIdx.x;
    int m0 = blockIdx.y * 128, n0 = blockIdx.x * 128;
    int wid = tid >> 6, lane = tid & 63;
    int wm = wid >> 1, wn = wid & 1, quad = lane >> 4, l15 = lane & 15;
    f32x4 acc[4][4] = {};
    for (int k0 = 0; k0 < DDIM; k0 += 64) {
        stage_async(As, xw, m0, k0, DDIM, wid, lane);
        stage_async(Bs, wcat, n0, k0, DDIM, wid, lane);
        __syncthreads();
        mma_tile(As, Bs, acc, wm, wn, quad, l15);
        __syncthreads();
    }
#pragma unroll
    for (int im = 0; im < 4; ++im) {
#pragma unroll
        for (int jn = 0; jn < 4; ++jn) {
            int n = n0 + wn * 64 + jn * 16 + l15;
            float bias = bcat[n];
            int blk = n >> 10, nf = n & 1023;
#pragma unroll
            for (int r = 0; r < 4; ++r) {
                int m = m0 + wm * 64 + im * 16 + quad * 4 + r;
                float z = acc[im][jn][r] + bias;
                size_t o = (size_t)m * DDIM + nf;
                if (blk == 0)      qb[o] = f2b(fmaxf(z, 0.f));
                else if (blk == 1) kb[o] = f2b(fmaxf(z, 0.f));
                else if (blk == 2) vb[o] = f2b(z);
                else               gA[o] = logf(1.f / (1.f + expf(-z)) + 1e-6f);
            }
        }
    }
}

// ---------------- transpose v -> vT [B][D][T] ----------------
__global__ void k_transpose_v(const u16* __restrict__ v, u16* __restrict__ vT) {
    __shared__ u16 tile[64][65];
    int b = blockIdx.z, s0 = blockIdx.x * 64, j0 = blockIdx.y * 64;
    int tx = threadIdx.x & 63, ty = threadIdx.x >> 6;
#pragma unroll
    for (int r = ty; r < 64; r += 4)
        tile[r][tx] = v[((size_t)(b * TSEQ + s0 + r) << 10) + j0 + tx];
    __syncthreads();
#pragma unroll
    for (int r = ty; r < 64; r += 4)
        vT[((size_t)(b * DDIM + j0 + r) << 12) + s0 + tx] = tile[tx][r];
}

// ---------------- gate scan (3 passes, chunks of 64 rows) ----------------
__global__ void k_scan_part(const float* __restrict__ gA, float* __restrict__ part) {
    int c = blockIdx.x, b = blockIdx.y, tid = threadIdx.x;
    float a0 = 0, a1 = 0, a2 = 0, a3 = 0;
    size_t base = ((size_t)(b * TSEQ + c * 64)) << 10;
    for (int s = 0; s < 64; ++s) {
        const float* row = gA + base + ((size_t)s << 10);
        a0 += row[tid]; a1 += row[tid + 256]; a2 += row[tid + 512]; a3 += row[tid + 768];
    }
    float* p = part + ((size_t)(b * 64 + c) << 10);
    p[tid] = a0; p[tid + 256] = a1; p[tid + 512] = a2; p[tid + 768] = a3;
}

__global__ __launch_bounds__(1024) void k_scan_sweep(float* __restrict__ part) {
    int b = blockIdx.x, tid = threadIdx.x;  // 1024 threads
    float run = 0;
    for (int c = 63; c >= 0; --c) {
        float* p = part + ((size_t)(b * 64 + c) << 10) + tid;
        float val = *p; *p = run; run += val;
    }
}

__global__ void k_scan_apply(const float* __restrict__ gA, const float* __restrict__ part,
                             u16* __restrict__ kb) {
    int c = blockIdx.x, b = blockIdx.y, tid = threadIdx.x;
    const float* p = part + ((size_t)(b * 64 + c) << 10);
    float r0 = p[tid], r1 = p[tid + 256], r2 = p[tid + 512], r3 = p[tid + 768];
    size_t base = ((size_t)(b * TSEQ + c * 64)) << 10;
    for (int s = 63; s >= 0; --s) {
        size_t ro = base + ((size_t)s << 10);
        r0 += gA[ro + tid];
        kb[ro + tid] = f2b(b2f(kb[ro + tid]) * expf(r0));
        r1 += gA[ro + tid + 256];
        kb[ro + tid + 256] = f2b(b2f(kb[ro + tid + 256]) * expf(r1));
        r2 += gA[ro + tid + 512];
        kb[ro + tid + 512] = f2b(b2f(kb[ro + tid + 512]) * expf(r2));
        r3 += gA[ro + tid + 768];
        kb[ro + tid + 768] = f2b(b2f(kb[ro + tid + 768]) * expf(r3));
    }
}

// ---------------- scores = q @ wk^T (causal), bf16 out + denom atomics ----------------
__global__ __launch_bounds__(256) void k_scores(
    const u16* __restrict__ qb, const u16* __restrict__ wkb,
    u16* __restrict__ scores, float* __restrict__ denom) {
    int si = blockIdx.x, ti = blockIdx.y, b = blockIdx.z;
    if (si > ti) return;
    __shared__ u16 As[128 * 64];
    __shared__ u16 Bs[128 * 64];
    int tid = threadIdx.x;
    const u16* A = qb + ((size_t)b << 22);
    const u16* Bm = wkb + ((size_t)b << 22);
    int t0 = ti * 128, s0 = si * 128;
    int wid = tid >> 6, lane = tid & 63;
    int wm = wid >> 1, wn = wid & 1, quad = lane >> 4, l15 = lane & 15;
    f32x4 acc[4][4] = {};
    for (int k0 = 0; k0 < DDIM; k0 += 64) {
        stage_async(As, A, t0, k0, DDIM, wid, lane);
        stage_async(Bs, Bm, s0, k0, DDIM, wid, lane);
        __syncthreads();
        mma_tile(As, Bs, acc, wm, wn, quad, l15);
        __syncthreads();
    }
#pragma unroll
    for (int im = 0; im < 4; ++im) {
#pragma unroll
        for (int r = 0; r < 4; ++r) {
            int trow = t0 + wm * 64 + im * 16 + quad * 4 + r;
            float rs = 0.f;
#pragma unroll
            for (int jn = 0; jn < 4; ++jn) {
                int s = s0 + wn * 64 + jn * 16 + l15;
                float val = acc[im][jn][r];
                if (s > trow) val = 0.f;
                rs += val;
                scores[((size_t)(b * TSEQ + trow) << 12) + s] = f2b(val);
            }
#pragma unroll
            for (int m = 1; m < 16; m <<= 1) rs += __shfl_xor(rs, m, 64);
            if (l15 == 0) atomicAdd(denom + (b << 12) + trow, rs);
        }
    }
}

// ---------------- num = scores @ v (causal K bound), divide by denom ----------------
__global__ __launch_bounds__(256) void k_num(
    const u16* __restrict__ scores, const u16* __restrict__ vT,
    const float* __restrict__ denom, float* __restrict__ out) {
    int ji = blockIdx.x, ti = blockIdx.y, b = blockIdx.z;
    __shared__ u16 As[128 * 64];
    __shared__ u16 Bs[128 * 64];
    int tid = threadIdx.x;
    const u16* A = scores + ((size_t)b << 24);  // [T][T]
    const u16* Bm = vT + ((size_t)b << 22);     // [D][T]
    int t0 = ti * 128, j0 = ji * 128;
    int wid = tid >> 6, lane = tid & 63;
    int wm = wid >> 1, wn = wid & 1, quad = lane >> 4, l15 = lane & 15;
    f32x4 acc[4][4] = {};
    int kmax = (ti + 1) * 128;
    for (int k0 = 0; k0 < kmax; k0 += 64) {
        stage_async(As, A, t0, k0, TSEQ, wid, lane);
        stage_async(Bs, Bm, j0, k0, TSEQ, wid, lane);
        __syncthreads();
        mma_tile(As, Bs, acc, wm, wn, quad, l15);
        __syncthreads();
    }
#pragma unroll
    for (int im = 0; im < 4; ++im) {
#pragma unroll
        for (int r = 0; r < 4; ++r) {
            int t = t0 + wm * 64 + im * 16 + quad * 4 + r;
            float den = denom[(b << 12) + t] + EPSV;
#pragma unroll
            for (int jn = 0; jn < 4; ++jn) {
                int j = j0 + wn * 64 + jn * 16 + l15;
                out[((size_t)(b * TSEQ + t) << 10) + j] = acc[im][jn][r] / den;
            }
        }
    }
}

// ---------------- workspace layout (bytes) ----------------
// persistent: q | wk | vT | denom | bcat
// early (overlaid by scores later): xw | wcat | v | gA | part
static const size_t OFF_Q      = 0;
static const size_t OFF_WK     = 33554432;
static const size_t OFF_VT     = 67108864;
static const size_t OFF_DENOM  = 100663296;
static const size_t OFF_BCAT   = 100728832;
static const size_t OFF_XW     = 100745216;
static const size_t OFF_WCAT   = 134299648;
static const size_t OFF_V      = 142688256;
static const size_t OFF_GA     = 176242688;
static const size_t OFF_PART   = 243351552;
static const size_t OFF_SCORES = OFF_XW;  // 134,217,728 B, overlays dead early region

extern "C" void kernel_launch(void* const* d_in, const int* in_sizes, int n_in,
                              void* d_out, int out_size, void* d_ws, size_t ws_size,
                              hipStream_t stream) {
    const float* x  = (const float*)d_in[0];
    const float* Wq = (const float*)d_in[1];
    const float* bq = (const float*)d_in[2];
    const float* Wk = (const float*)d_in[3];
    const float* bk = (const float*)d_in[4];
    const float* Wv = (const float*)d_in[5];
    const float* bv = (const float*)d_in[6];
    const float* Wa = (const float*)d_in[7];
    const float* ba = (const float*)d_in[8];
    float* out = (float*)d_out;

    char* W = (char*)d_ws;
    u16* qb      = (u16*)(W + OFF_Q);
    u16* wkb     = (u16*)(W + OFF_WK);
    u16* vT      = (u16*)(W + OFF_VT);
    float* denom = (float*)(W + OFF_DENOM);
    float* bcat  = (float*)(W + OFF_BCAT);
    u16* xw      = (u16*)(W + OFF_XW);
    u16* wcat    = (u16*)(W + OFF_WCAT);
    u16* vb      = (u16*)(W + OFF_V);
    float* gA    = (float*)(W + OFF_GA);
    float* part  = (float*)(W + OFF_PART);
    u16* scores  = (u16*)(W + OFF_SCORES);

    hipMemsetAsync(denom, 0, (size_t)NB * TSEQ * sizeof(float), stream);

    k_conv_x<<<16384, 256, 0, stream>>>(x, xw);
    k_conv_w<<<4096, 256, 0, stream>>>(Wq, Wk, Wv, Wa, wcat);
    k_conv_b<<<16, 256, 0, stream>>>(bq, bk, bv, ba, bcat);

    k_gemm_qkva<<<dim3(32, 128), 256, 0, stream>>>(xw, wcat, bcat, qb, wkb, vb, gA);

    k_transpose_v<<<dim3(64, 16, NB), 256, 0, stream>>>(vb, vT);

    k_scan_part<<<dim3(64, NB), 256, 0, stream>>>(gA, part);
    k_scan_sweep<<<NB, 1024, 0, stream>>>(part);
    k_scan_apply<<<dim3(64, NB), 256, 0, stream>>>(gA, part, wkb);

    k_scores<<<dim3(32, 32, NB), 256, 0, stream>>>(qb, wkb, scores, denom);

    k_num<<<dim3(8, 32, NB), 256, 0, stream>>>(scores, vT, denom, out);
}

// Round 3
// 793.906 us; speedup vs baseline: 1.1651x; 1.1153x over previous
//
#include <hip/hip_runtime.h>

typedef unsigned short u16;
typedef unsigned int u32;

typedef __bf16 bf16x8 __attribute__((ext_vector_type(8)));
typedef float f32x4 __attribute__((ext_vector_type(4)));

#define TSEQ 4096
#define DDIM 1024
#define NB 4
#define EPSV 1e-6f

__device__ __forceinline__ u16 f2b(float f) {
    union { float f; u32 u; } v; v.f = f;
    u32 r = v.u + 0x7FFFu + ((v.u >> 16) & 1u);
    return (u16)(r >> 16);
}
__device__ __forceinline__ float b2f(u16 h) {
    union { u32 u; float f; } v; v.u = ((u32)h) << 16; return v.f;
}

// ---------------- conversion kernels ----------------
__global__ void k_conv_x(const float* __restrict__ x, u16* __restrict__ xw) {
    size_t i = ((size_t)blockIdx.x * 256 + threadIdx.x) * 4;
    float4 f = *(const float4*)(x + i);
    ushort4 u;
    u.x = f2b(f.x); u.y = f2b(f.y); u.z = f2b(f.z); u.w = f2b(f.w);
    *(ushort4*)(xw + i) = u;
}

__global__ void k_conv_w(const float* __restrict__ wq, const float* __restrict__ wk,
                         const float* __restrict__ wv, const float* __restrict__ wa,
                         u16* __restrict__ wcat) {
    size_t i = ((size_t)blockIdx.x * 256 + threadIdx.x) * 4;
    int sel = (int)(i >> 20);
    const float* src = (sel == 0) ? wq : (sel == 1) ? wk : (sel == 2) ? wv : wa;
    size_t loc = i & ((1u << 20) - 1);
    float4 f = *(const float4*)(src + loc);
    ushort4 u;
    u.x = f2b(f.x); u.y = f2b(f.y); u.z = f2b(f.z); u.w = f2b(f.w);
    *(ushort4*)(wcat + i) = u;
}

__global__ void k_conv_b(const float* __restrict__ bq, const float* __restrict__ bk,
                         const float* __restrict__ bv, const float* __restrict__ ba,
                         float* __restrict__ bcat) {
    int j = blockIdx.x * 256 + threadIdx.x;  // 0..4095
    int sel = j >> 10;
    const float* src = (sel == 0) ? bq : (sel == 1) ? bk : (sel == 2) ? bv : ba;
    bcat[j] = src[j & 1023];
}

// ---------------- GEMM core helpers ----------------
// Async-stage a 128-row x 64-col bf16 tile (row-major, stride ld elements) into LDS,
// with XOR bank swizzle: LDS position (r, h) [h = 16B granule 0..7] holds global
// granule (r, h ^ (r&7)). global_load_lds forces dst = chunk_base + lane*16, so the
// swizzle is applied on the SOURCE address. Read side must un-swizzle (see mma_tile).
// Kills the 16-way bank conflict of the unswizzled row-major layout (row stride
// 128 B == 32 banks made the bank index row-independent).
__device__ __forceinline__ void stage_async(u16* __restrict__ dst, const u16* __restrict__ src,
                                            int row0, int k0, int ld, int wid, int lane) {
#pragma unroll
    for (int c = 0; c < 4; ++c) {
        int rbase = wid * 32 + c * 8;
        int r = rbase + (lane >> 3);
        int hs = (lane & 7) ^ (r & 7);      // swizzled source granule
        const char* g = (const char*)src + ((size_t)(row0 + r) * ld + k0) * 2 + hs * 16;
        char* l = (char*)dst + rbase * 128 + lane * 16;
        __builtin_amdgcn_global_load_lds((const __attribute__((address_space(1))) u32*)g,
                                         (__attribute__((address_space(3))) u32*)l, 16, 0, 0);
    }
}

// One BK=64 step of MFMA on staged tiles. Wave computes 64x64 (4x4 of 16x16x32).
// Fragment reads un-swizzle: granule cg = (kk+quad*8)/8 lives at LDS granule
// cg ^ (row&7). Banks = 4*(cg^(row&7)) mod 32 -> full 32-bank coverage per
// 8 lanes, 2-way aliasing only (free per m136).
__device__ __forceinline__ void mma_tile(const u16* __restrict__ As, const u16* __restrict__ Bs,
                                         f32x4 acc[4][4], int wm, int wn, int quad, int l15) {
#pragma unroll
    for (int kk = 0; kk < 64; kk += 32) {
        int cg = (kk >> 3) + quad;  // granule index of this fragment's 16 B
        bf16x8 a[4], b[4];
#pragma unroll
        for (int i = 0; i < 4; ++i) {
            int arow = wm * 64 + i * 16 + l15;
            int brow = wn * 64 + i * 16 + l15;
            a[i] = *(const bf16x8*)(As + arow * 64 + ((cg ^ (arow & 7)) << 3));
            b[i] = *(const bf16x8*)(Bs + brow * 64 + ((cg ^ (brow & 7)) << 3));
        }
#pragma unroll
        for (int i = 0; i < 4; ++i)
#pragma unroll
            for (int j = 0; j < 4; ++j)
                acc[i][j] = __builtin_amdgcn_mfma_f32_16x16x32_bf16(a[i], b[j], acc[i][j], 0, 0, 0);
    }
}

// ---------------- fused QKVA projection GEMM ----------------
// C[m,n] = sum_k x[m,k] * Wcat[n,k]; epilogue splits n into q/k/v/A outputs.
__global__ __launch_bounds__(256) void k_gemm_qkva(
    const u16* __restrict__ xw, const u16* __restrict__ wcat, const float* __restrict__ bcat,
    u16* __restrict__ qb, u16* __restrict__ kb, u16* __restrict__ vb, float* __restrict__ gA) {
    __shared__ u16 As[128 * 64];
    __shared__ u16 Bs[128 * 64];
    int tid = threadIdx.x;
    int m0 = blockIdx.y * 128, n0 = blockIdx.x * 128;
    int wid = tid >> 6, lane = tid & 63;
    int wm = wid >> 1, wn = wid & 1, quad = lane >> 4, l15 = lane & 15;
    f32x4 acc[4][4] = {};
    for (int k0 = 0; k0 < DDIM; k0 += 64) {
        stage_async(As, xw, m0, k0, DDIM, wid, lane);
        stage_async(Bs, wcat, n0, k0, DDIM, wid, lane);
        __syncthreads();
        mma_tile(As, Bs, acc, wm, wn, quad, l15);
        __syncthreads();
    }
#pragma unroll
    for (int im = 0; im < 4; ++im) {
#pragma unroll
        for (int jn = 0; jn < 4; ++jn) {
            int n = n0 + wn * 64 + jn * 16 + l15;
            float bias = bcat[n];
            int blk = n >> 10, nf = n & 1023;
#pragma unroll
            for (int r = 0; r < 4; ++r) {
                int m = m0 + wm * 64 + im * 16 + quad * 4 + r;
                float z = acc[im][jn][r] + bias;
                size_t o = (size_t)m * DDIM + nf;
                if (blk == 0)      qb[o] = f2b(fmaxf(z, 0.f));
                else if (blk == 1) kb[o] = f2b(fmaxf(z, 0.f));
                else if (blk == 2) vb[o] = f2b(z);
                else               gA[o] = logf(1.f / (1.f + expf(-z)) + 1e-6f);
            }
        }
    }
}

// ---------------- transpose v -> vT [B][D][T] ----------------
__global__ void k_transpose_v(const u16* __restrict__ v, u16* __restrict__ vT) {
    __shared__ u16 tile[64][65];
    int b = blockIdx.z, s0 = blockIdx.x * 64, j0 = blockIdx.y * 64;
    int tx = threadIdx.x & 63, ty = threadIdx.x >> 6;
#pragma unroll
    for (int r = ty; r < 64; r += 4)
        tile[r][tx] = v[((size_t)(b * TSEQ + s0 + r) << 10) + j0 + tx];
    __syncthreads();
#pragma unroll
    for (int r = ty; r < 64; r += 4)
        vT[((size_t)(b * DDIM + j0 + r) << 12) + s0 + tx] = tile[tx][r];
}

// ---------------- gate scan (3 passes, chunks of 64 rows) ----------------
__global__ void k_scan_part(const float* __restrict__ gA, float* __restrict__ part) {
    int c = blockIdx.x, b = blockIdx.y, tid = threadIdx.x;
    float a0 = 0, a1 = 0, a2 = 0, a3 = 0;
    size_t base = ((size_t)(b * TSEQ + c * 64)) << 10;
    for (int s = 0; s < 64; ++s) {
        const float* row = gA + base + ((size_t)s << 10);
        a0 += row[tid]; a1 += row[tid + 256]; a2 += row[tid + 512]; a3 += row[tid + 768];
    }
    float* p = part + ((size_t)(b * 64 + c) << 10);
    p[tid] = a0; p[tid + 256] = a1; p[tid + 512] = a2; p[tid + 768] = a3;
}

__global__ __launch_bounds__(1024) void k_scan_sweep(float* __restrict__ part) {
    int b = blockIdx.x, tid = threadIdx.x;  // 1024 threads
    float run = 0;
    for (int c = 63; c >= 0; --c) {
        float* p = part + ((size_t)(b * 64 + c) << 10) + tid;
        float val = *p; *p = run; run += val;
    }
}

__global__ void k_scan_apply(const float* __restrict__ gA, const float* __restrict__ part,
                             u16* __restrict__ kb) {
    int c = blockIdx.x, b = blockIdx.y, tid = threadIdx.x;
    const float* p = part + ((size_t)(b * 64 + c) << 10);
    float r0 = p[tid], r1 = p[tid + 256], r2 = p[tid + 512], r3 = p[tid + 768];
    size_t base = ((size_t)(b * TSEQ + c * 64)) << 10;
    for (int s = 63; s >= 0; --s) {
        size_t ro = base + ((size_t)s << 10);
        r0 += gA[ro + tid];
        kb[ro + tid] = f2b(b2f(kb[ro + tid]) * expf(r0));
        r1 += gA[ro + tid + 256];
        kb[ro + tid + 256] = f2b(b2f(kb[ro + tid + 256]) * expf(r1));
        r2 += gA[ro + tid + 512];
        kb[ro + tid + 512] = f2b(b2f(kb[ro + tid + 512]) * expf(r2));
        r3 += gA[ro + tid + 768];
        kb[ro + tid + 768] = f2b(b2f(kb[ro + tid + 768]) * expf(r3));
    }
}

// ---------------- scores = q @ wk^T (causal), bf16 out + denom atomics ----------------
__global__ __launch_bounds__(256) void k_scores(
    const u16* __restrict__ qb, const u16* __restrict__ wkb,
    u16* __restrict__ scores, float* __restrict__ denom) {
    int si = blockIdx.x, ti = blockIdx.y, b = blockIdx.z;
    if (si > ti) return;
    __shared__ u16 As[128 * 64];
    __shared__ u16 Bs[128 * 64];
    int tid = threadIdx.x;
    const u16* A = qb + ((size_t)b << 22);
    const u16* Bm = wkb + ((size_t)b << 22);
    int t0 = ti * 128, s0 = si * 128;
    int wid = tid >> 6, lane = tid & 63;
    int wm = wid >> 1, wn = wid & 1, quad = lane >> 4, l15 = lane & 15;
    f32x4 acc[4][4] = {};
    for (int k0 = 0; k0 < DDIM; k0 += 64) {
        stage_async(As, A, t0, k0, DDIM, wid, lane);
        stage_async(Bs, Bm, s0, k0, DDIM, wid, lane);
        __syncthreads();
        mma_tile(As, Bs, acc, wm, wn, quad, l15);
        __syncthreads();
    }
#pragma unroll
    for (int im = 0; im < 4; ++im) {
#pragma unroll
        for (int r = 0; r < 4; ++r) {
            int trow = t0 + wm * 64 + im * 16 + quad * 4 + r;
            float rs = 0.f;
#pragma unroll
            for (int jn = 0; jn < 4; ++jn) {
                int s = s0 + wn * 64 + jn * 16 + l15;
                float val = acc[im][jn][r];
                if (s > trow) val = 0.f;
                rs += val;
                scores[((size_t)(b * TSEQ + trow) << 12) + s] = f2b(val);
            }
#pragma unroll
            for (int m = 1; m < 16; m <<= 1) rs += __shfl_xor(rs, m, 64);
            if (l15 == 0) atomicAdd(denom + (b << 12) + trow, rs);
        }
    }
}

// ---------------- num = scores @ v (causal K bound), divide by denom ----------------
__global__ __launch_bounds__(256) void k_num(
    const u16* __restrict__ scores, const u16* __restrict__ vT,
    const float* __restrict__ denom, float* __restrict__ out) {
    int ji = blockIdx.x, ti = blockIdx.y, b = blockIdx.z;
    __shared__ u16 As[128 * 64];
    __shared__ u16 Bs[128 * 64];
    int tid = threadIdx.x;
    const u16* A = scores + ((size_t)b << 24);  // [T][T]
    const u16* Bm = vT + ((size_t)b << 22);     // [D][T]
    int t0 = ti * 128, j0 = ji * 128;
    int wid = tid >> 6, lane = tid & 63;
    int wm = wid >> 1, wn = wid & 1, quad = lane >> 4, l15 = lane & 15;
    f32x4 acc[4][4] = {};
    int kmax = (ti + 1) * 128;
    for (int k0 = 0; k0 < kmax; k0 += 64) {
        stage_async(As, A, t0, k0, TSEQ, wid, lane);
        stage_async(Bs, Bm, j0, k0, TSEQ, wid, lane);
        __syncthreads();
        mma_tile(As, Bs, acc, wm, wn, quad, l15);
        __syncthreads();
    }
#pragma unroll
    for (int im = 0; im < 4; ++im) {
#pragma unroll
        for (int r = 0; r < 4; ++r) {
            int t = t0 + wm * 64 + im * 16 + quad * 4 + r;
            float den = denom[(b << 12) + t] + EPSV;
#pragma unroll
            for (int jn = 0; jn < 4; ++jn) {
                int j = j0 + wn * 64 + jn * 16 + l15;
                out[((size_t)(b * TSEQ + t) << 10) + j] = acc[im][jn][r] / den;
            }
        }
    }
}

// ---------------- workspace layout (bytes) ----------------
// persistent: q | wk | vT | denom | bcat
// early (overlaid by scores later): xw | wcat | v | gA | part
static const size_t OFF_Q      = 0;
static const size_t OFF_WK     = 33554432;
static const size_t OFF_VT     = 67108864;
static const size_t OFF_DENOM  = 100663296;
static const size_t OFF_BCAT   = 100728832;
static const size_t OFF_XW     = 100745216;
static const size_t OFF_WCAT   = 134299648;
static const size_t OFF_V      = 142688256;
static const size_t OFF_GA     = 176242688;
static const size_t OFF_PART   = 243351552;
static const size_t OFF_SCORES = OFF_XW;  // 134,217,728 B, overlays dead early region

extern "C" void kernel_launch(void* const* d_in, const int* in_sizes, int n_in,
                              void* d_out, int out_size, void* d_ws, size_t ws_size,
                              hipStream_t stream) {
    const float* x  = (const float*)d_in[0];
    const float* Wq = (const float*)d_in[1];
    const float* bq = (const float*)d_in[2];
    const float* Wk = (const float*)d_in[3];
    const float* bk = (const float*)d_in[4];
    const float* Wv = (const float*)d_in[5];
    const float* bv = (const float*)d_in[6];
    const float* Wa = (const float*)d_in[7];
    const float* ba = (const float*)d_in[8];
    float* out = (float*)d_out;

    char* W = (char*)d_ws;
    u16* qb      = (u16*)(W + OFF_Q);
    u16* wkb     = (u16*)(W + OFF_WK);
    u16* vT      = (u16*)(W + OFF_VT);
    float* denom = (float*)(W + OFF_DENOM);
    float* bcat  = (float*)(W + OFF_BCAT);
    u16* xw      = (u16*)(W + OFF_XW);
    u16* wcat    = (u16*)(W + OFF_WCAT);
    u16* vb      = (u16*)(W + OFF_V);
    float* gA    = (float*)(W + OFF_GA);
    float* part  = (float*)(W + OFF_PART);
    u16* scores  = (u16*)(W + OFF_SCORES);

    hipMemsetAsync(denom, 0, (size_t)NB * TSEQ * sizeof(float), stream);

    k_conv_x<<<16384, 256, 0, stream>>>(x, xw);
    k_conv_w<<<4096, 256, 0, stream>>>(Wq, Wk, Wv, Wa, wcat);
    k_conv_b<<<16, 256, 0, stream>>>(bq, bk, bv, ba, bcat);

    k_gemm_qkva<<<dim3(32, 128), 256, 0, stream>>>(xw, wcat, bcat, qb, wkb, vb, gA);

    k_transpose_v<<<dim3(64, 16, NB), 256, 0, stream>>>(vb, vT);

    k_scan_part<<<dim3(64, NB), 256, 0, stream>>>(gA, part);
    k_scan_sweep<<<NB, 1024, 0, stream>>>(part);
    k_scan_apply<<<dim3(64, NB), 256, 0, stream>>>(gA, part, wkb);

    k_scores<<<dim3(32, 32, NB), 256, 0, stream>>>(qb, wkb, scores, denom);

    k_num<<<dim3(8, 32, NB), 256, 0, stream>>>(scores, vT, denom, out);
}

// Round 5
// 718.657 us; speedup vs baseline: 1.2871x; 1.1047x over previous
//
#include <hip/hip_runtime.h>

typedef unsigned short u16;
typedef unsigned int u32;

typedef __bf16 bf16x8 __attribute__((ext_vector_type(8)));
typedef float f32x4 __attribute__((ext_vector_type(4)));
typedef u16 u16x8 __attribute__((ext_vector_type(8)));

#define TSEQ 4096
#define DDIM 1024
#define NB 4
#define EPSV 1e-6f
// bounce-buffer row pitch in u16 (272 B = 17*16 -> rows stay 16B-aligned, banks rotate)
#define CPITCH 136

__device__ __forceinline__ u16 f2b(float f) {
    union { float f; u32 u; } v; v.f = f;
    u32 r = v.u + 0x7FFFu + ((v.u >> 16) & 1u);
    return (u16)(r >> 16);
}
__device__ __forceinline__ float b2f(u16 h) {
    union { u32 u; float f; } v; v.u = ((u32)h) << 16; return v.f;
}

// ---------------- merged prep: x->bf16, W->bf16 concat, bias concat ----------------
__global__ void k_prep(const float* __restrict__ x,
                       const float* __restrict__ wq, const float* __restrict__ wk,
                       const float* __restrict__ wv, const float* __restrict__ wa,
                       const float* __restrict__ bq, const float* __restrict__ bk,
                       const float* __restrict__ bv, const float* __restrict__ ba,
                       u16* __restrict__ xw, u16* __restrict__ wcat, float* __restrict__ bcat) {
    int bid = blockIdx.x;
    if (bid < 16384) {
        size_t i = ((size_t)bid * 256 + threadIdx.x) * 4;
        float4 f = *(const float4*)(x + i);
        ushort4 u;
        u.x = f2b(f.x); u.y = f2b(f.y); u.z = f2b(f.z); u.w = f2b(f.w);
        *(ushort4*)(xw + i) = u;
    } else if (bid < 20480) {
        size_t i = ((size_t)(bid - 16384) * 256 + threadIdx.x) * 4;
        int sel = (int)(i >> 20);
        const float* src = (sel == 0) ? wq : (sel == 1) ? wk : (sel == 2) ? wv : wa;
        size_t loc = i & ((1u << 20) - 1);
        float4 f = *(const float4*)(src + loc);
        ushort4 u;
        u.x = f2b(f.x); u.y = f2b(f.y); u.z = f2b(f.z); u.w = f2b(f.w);
        *(ushort4*)(wcat + i) = u;
    } else {
#pragma unroll
        for (int c = 0; c < 16; ++c) {
            int j = c * 256 + threadIdx.x;
            int sel = j >> 10;
            const float* src = (sel == 0) ? bq : (sel == 1) ? bk : (sel == 2) ? bv : ba;
            bcat[j] = src[j & 1023];
        }
    }
}

// ---------------- GEMM core helpers ----------------
// Async-stage a 128x64 bf16 tile into LDS with XOR bank swizzle (see round 3).
__device__ __forceinline__ void stage_async(u16* __restrict__ dst, const u16* __restrict__ src,
                                            int row0, int k0, int ld, int wid, int lane) {
#pragma unroll
    for (int c = 0; c < 4; ++c) {
        int rbase = wid * 32 + c * 8;
        int r = rbase + (lane >> 3);
        int hs = (lane & 7) ^ (r & 7);      // swizzled source granule
        const char* g = (const char*)src + ((size_t)(row0 + r) * ld + k0) * 2 + hs * 16;
        char* l = (char*)dst + rbase * 128 + lane * 16;
        __builtin_amdgcn_global_load_lds((const __attribute__((address_space(1))) u32*)g,
                                         (__attribute__((address_space(3))) u32*)l, 16, 0, 0);
    }
}

// One BK=64 MFMA step; un-swizzles fragment reads.
__device__ __forceinline__ void mma_tile(const u16* __restrict__ As, const u16* __restrict__ Bs,
                                         f32x4 acc[4][4], int wm, int wn, int quad, int l15) {
#pragma unroll
    for (int kk = 0; kk < 64; kk += 32) {
        int cg = (kk >> 3) + quad;
        bf16x8 a[4], b[4];
#pragma unroll
        for (int i = 0; i < 4; ++i) {
            int arow = wm * 64 + i * 16 + l15;
            int brow = wn * 64 + i * 16 + l15;
            a[i] = *(const bf16x8*)(As + arow * 64 + ((cg ^ (arow & 7)) << 3));
            b[i] = *(const bf16x8*)(Bs + brow * 64 + ((cg ^ (brow & 7)) << 3));
        }
#pragma unroll
        for (int i = 0; i < 4; ++i)
#pragma unroll
            for (int j = 0; j < 4; ++j)
                acc[i][j] = __builtin_amdgcn_mfma_f32_16x16x32_bf16(a[i], b[j], acc[i][j], 0, 0, 0);
    }
}

// ---------------- fused QKVA projection GEMM ----------------
// n-tile -> output is block-uniform: x 0-7 q, 8-15 k, 16-23 v (written transposed
// into vT, replacing the separate transpose kernel), 24-31 gA (f32 log-sigmoid).
__global__ __launch_bounds__(256) void k_gemm_qkva(
    const u16* __restrict__ xw, const u16* __restrict__ wcat, const float* __restrict__ bcat,
    u16* __restrict__ qb, u16* __restrict__ kb, u16* __restrict__ vT, float* __restrict__ gA) {
    __shared__ __align__(16) char smem[CPITCH * 128 * 2];  // staging (32KB) U bf16 bounce (34KB)
    u16* As = (u16*)smem;
    u16* Bs = (u16*)(smem + 16384);
    int tid = threadIdx.x;
    int m0 = blockIdx.y * 128, n0 = blockIdx.x * 128;
    int wid = tid >> 6, lane = tid & 63;
    int wm = wid >> 1, wn = wid & 1, quad = lane >> 4, l15 = lane & 15;
    f32x4 acc[4][4] = {};
    for (int k0 = 0; k0 < DDIM; k0 += 64) {
        stage_async(As, xw, m0, k0, DDIM, wid, lane);
        stage_async(Bs, wcat, n0, k0, DDIM, wid, lane);
        __syncthreads();
        mma_tile(As, Bs, acc, wm, wn, quad, l15);
        __syncthreads();
    }
    int blk = n0 >> 10, nf0 = n0 & 1023;
    if (blk < 3) {
        // bf16 outputs: bounce through LDS, store vectorized.
        u16* Cs = (u16*)smem;
#pragma unroll
        for (int im = 0; im < 4; ++im)
#pragma unroll
        for (int jn = 0; jn < 4; ++jn) {
            float bias = bcat[n0 + wn * 64 + jn * 16 + l15];
#pragma unroll
            for (int r = 0; r < 4; ++r) {
                float z = acc[im][jn][r] + bias;
                if (blk < 2) z = fmaxf(z, 0.f);
                Cs[(wm * 64 + im * 16 + quad * 4 + r) * CPITCH + wn * 64 + jn * 16 + l15] = f2b(z);
            }
        }
        __syncthreads();
        if (blk < 2) {
            u16* dst = (blk == 0) ? qb : kb;
            int r = tid >> 1, ch = (tid & 1) * 64;
            size_t rowo = (size_t)(m0 + r) * DDIM + nf0 + ch;
#pragma unroll
            for (int i = 0; i < 8; ++i)
                *(u16x8*)(dst + rowo + i * 8) = *(const u16x8*)(Cs + r * CPITCH + ch + i * 8);
        } else {
            // v: read bounce transposed, write vT[b][j][t] coalesced.
            int j = tid >> 1, th = (tid & 1) * 64;
            int bB = m0 >> 12, t0m = m0 & 4095;
            size_t rowo = (((size_t)(bB * DDIM + nf0 + j)) << 12) + t0m + th;
#pragma unroll
            for (int i = 0; i < 8; ++i) {
                u16x8 vv;
#pragma unroll
                for (int e = 0; e < 8; ++e)
                    vv[e] = Cs[(th + i * 8 + e) * CPITCH + j];
                *(u16x8*)(vT + rowo + i * 8) = vv;
            }
        }
    } else {
        // gA: f32 scalar stores are already 64B-segment coalesced; keep direct.
#pragma unroll
        for (int im = 0; im < 4; ++im)
#pragma unroll
        for (int jn = 0; jn < 4; ++jn) {
            int n = n0 + wn * 64 + jn * 16 + l15;
            float bias = bcat[n];
            int nf = n & 1023;
#pragma unroll
            for (int r = 0; r < 4; ++r) {
                int m = m0 + wm * 64 + im * 16 + quad * 4 + r;
                float z = acc[im][jn][r] + bias;
                gA[(size_t)m * DDIM + nf] = logf(1.f / (1.f + expf(-z)) + 1e-6f);
            }
        }
    }
}

// ---------------- gate scan (3 passes, chunks of 64 rows) ----------------
__global__ void k_scan_part(const float* __restrict__ gA, float* __restrict__ part) {
    int c = blockIdx.x, b = blockIdx.y, tid = threadIdx.x;
    float a0 = 0, a1 = 0, a2 = 0, a3 = 0;
    size_t base = ((size_t)(b * TSEQ + c * 64)) << 10;
    for (int s = 0; s < 64; ++s) {
        const float* row = gA + base + ((size_t)s << 10);
        a0 += row[tid]; a1 += row[tid + 256]; a2 += row[tid + 512]; a3 += row[tid + 768];
    }
    float* p = part + ((size_t)(b * 64 + c) << 10);
    p[tid] = a0; p[tid + 256] = a1; p[tid + 512] = a2; p[tid + 768] = a3;
}

__global__ __launch_bounds__(1024) void k_scan_sweep(float* __restrict__ part) {
    int b = blockIdx.x, tid = threadIdx.x;  // 1024 threads
    float run = 0;
    for (int c = 63; c >= 0; --c) {
        float* p = part + ((size_t)(b * 64 + c) << 10) + tid;
        float val = *p; *p = run; run += val;
    }
}

__global__ void k_scan_apply(const float* __restrict__ gA, const float* __restrict__ part,
                             u16* __restrict__ kb) {
    int c = blockIdx.x, b = blockIdx.y, tid = threadIdx.x;
    const float* p = part + ((size_t)(b * 64 + c) << 10);
    float r0 = p[tid], r1 = p[tid + 256], r2 = p[tid + 512], r3 = p[tid + 768];
    size_t base = ((size_t)(b * TSEQ + c * 64)) << 10;
    for (int s = 63; s >= 0; --s) {
        size_t ro = base + ((size_t)s << 10);
        r0 += gA[ro + tid];
        kb[ro + tid] = f2b(b2f(kb[ro + tid]) * expf(r0));
        r1 += gA[ro + tid + 256];
        kb[ro + tid + 256] = f2b(b2f(kb[ro + tid + 256]) * expf(r1));
        r2 += gA[ro + tid + 512];
        kb[ro + tid + 512] = f2b(b2f(kb[ro + tid + 512]) * expf(r2));
        r3 += gA[ro + tid + 768];
        kb[ro + tid + 768] = f2b(b2f(kb[ro + tid + 768]) * expf(r3));
    }
}

// ---------------- scores = q @ wk^T (causal), bf16 out + denom atomics ----------------
__global__ __launch_bounds__(256) void k_scores(
    const u16* __restrict__ qb, const u16* __restrict__ wkb,
    u16* __restrict__ scores, float* __restrict__ denom) {
    int si = blockIdx.x, ti = blockIdx.y, b = blockIdx.z;
    if (si > ti) return;
    __shared__ __align__(16) char smem[CPITCH * 128 * 2];
    u16* As = (u16*)smem;
    u16* Bs = (u16*)(smem + 16384);
    int tid = threadIdx.x;
    const u16* A = qb + ((size_t)b << 22);
    const u16* Bm = wkb + ((size_t)b << 22);
    int t0 = ti * 128, s0 = si * 128;
    int wid = tid >> 6, lane = tid & 63;
    int wm = wid >> 1, wn = wid & 1, quad = lane >> 4, l15 = lane & 15;
    f32x4 acc[4][4] = {};
    for (int k0 = 0; k0 < DDIM; k0 += 64) {
        stage_async(As, A, t0, k0, DDIM, wid, lane);
        stage_async(Bs, Bm, s0, k0, DDIM, wid, lane);
        __syncthreads();
        mma_tile(As, Bs, acc, wm, wn, quad, l15);
        __syncthreads();
    }
    u16* Cs = (u16*)smem;
#pragma unroll
    for (int im = 0; im < 4; ++im) {
#pragma unroll
        for (int r = 0; r < 4; ++r) {
            int trow = t0 + wm * 64 + im * 16 + quad * 4 + r;
            float rs = 0.f;
#pragma unroll
            for (int jn = 0; jn < 4; ++jn) {
                int s = s0 + wn * 64 + jn * 16 + l15;
                float val = acc[im][jn][r];
                if (s > trow) val = 0.f;
                rs += val;
                Cs[(wm * 64 + im * 16 + quad * 4 + r) * CPITCH + wn * 64 + jn * 16 + l15] = f2b(val);
            }
#pragma unroll
            for (int m = 1; m < 16; m <<= 1) rs += __shfl_xor(rs, m, 64);
            if (l15 == 0) atomicAdd(denom + (b << 12) + trow, rs);
        }
    }
    __syncthreads();
    int r = tid >> 1, ch = (tid & 1) * 64;
    size_t rowo = ((size_t)(b * TSEQ + t0 + r) << 12) + s0 + ch;
#pragma unroll
    for (int i = 0; i < 8; ++i)
        *(u16x8*)(scores + rowo + i * 8) = *(const u16x8*)(Cs + r * CPITCH + ch + i * 8);
}

// ---------------- num = scores @ v (causal K bound), divide by denom ----------------
__global__ __launch_bounds__(256) void k_num(
    const u16* __restrict__ scores, const u16* __restrict__ vT,
    const float* __restrict__ denom, float* __restrict__ out) {
    int ji = blockIdx.x, ti = blockIdx.y, b = blockIdx.z;
    __shared__ __align__(16) u16 As[128 * 64];
    __shared__ __align__(16) u16 Bs[128 * 64];
    int tid = threadIdx.x;
    const u16* A = scores + ((size_t)b << 24);  // [T][T]
    const u16* Bm = vT + ((size_t)b << 22);     // [D][T]
    int t0 = ti * 128, j0 = ji * 128;
    int wid = tid >> 6, lane = tid & 63;
    int wm = wid >> 1, wn = wid & 1, quad = lane >> 4, l15 = lane & 15;
    f32x4 acc[4][4] = {};
    int kmax = (ti + 1) * 128;
    for (int k0 = 0; k0 < kmax; k0 += 64) {
        stage_async(As, A, t0, k0, TSEQ, wid, lane);
        stage_async(Bs, Bm, j0, k0, TSEQ, wid, lane);
        __syncthreads();
        mma_tile(As, Bs, acc, wm, wn, quad, l15);
        __syncthreads();
    }
#pragma unroll
    for (int im = 0; im < 4; ++im) {
#pragma unroll
        for (int r = 0; r < 4; ++r) {
            int t = t0 + wm * 64 + im * 16 + quad * 4 + r;
            float den = denom[(b << 12) + t] + EPSV;
#pragma unroll
            for (int jn = 0; jn < 4; ++jn) {
                int j = j0 + wn * 64 + jn * 16 + l15;
                out[((size_t)(b * TSEQ + t) << 10) + j] = acc[im][jn][r] / den;
            }
        }
    }
}

// ---------------- workspace layout (bytes) ----------------
static const size_t OFF_Q      = 0;
static const size_t OFF_WK     = 33554432;
static const size_t OFF_VT     = 67108864;
static const size_t OFF_DENOM  = 100663296;
static const size_t OFF_BCAT   = 100728832;
static const size_t OFF_XW     = 100745216;
static const size_t OFF_WCAT   = 134299648;
static const size_t OFF_GA     = 176242688;
static const size_t OFF_PART   = 243351552;
static const size_t OFF_SCORES = OFF_XW;  // 134,217,728 B, overlays dead early region

extern "C" void kernel_launch(void* const* d_in, const int* in_sizes, int n_in,
                              void* d_out, int out_size, void* d_ws, size_t ws_size,
                              hipStream_t stream) {
    const float* x  = (const float*)d_in[0];
    const float* Wq = (const float*)d_in[1];
    const float* bq = (const float*)d_in[2];
    const float* Wk = (const float*)d_in[3];
    const float* bk = (const float*)d_in[4];
    const float* Wv = (const float*)d_in[5];
    const float* bv = (const float*)d_in[6];
    const float* Wa = (const float*)d_in[7];
    const float* ba = (const float*)d_in[8];
    float* out = (float*)d_out;

    char* W = (char*)d_ws;
    u16* qb      = (u16*)(W + OFF_Q);
    u16* wkb     = (u16*)(W + OFF_WK);
    u16* vT      = (u16*)(W + OFF_VT);
    float* denom = (float*)(W + OFF_DENOM);
    float* bcat  = (float*)(W + OFF_BCAT);
    u16* xw      = (u16*)(W + OFF_XW);
    u16* wcat    = (u16*)(W + OFF_WCAT);
    float* gA    = (float*)(W + OFF_GA);
    float* part  = (float*)(W + OFF_PART);
    u16* scores  = (u16*)(W + OFF_SCORES);

    hipMemsetAsync(denom, 0, (size_t)NB * TSEQ * sizeof(float), stream);

    k_prep<<<20481, 256, 0, stream>>>(x, Wq, Wk, Wv, Wa, bq, bk, bv, ba, xw, wcat, bcat);

    k_gemm_qkva<<<dim3(32, 128), 256, 0, stream>>>(xw, wcat, bcat, qb, wkb, vT, gA);

    k_scan_part<<<dim3(64, NB), 256, 0, stream>>>(gA, part);
    k_scan_sweep<<<NB, 1024, 0, stream>>>(part);
    k_scan_apply<<<dim3(64, NB), 256, 0, stream>>>(gA, part, wkb);

    k_scores<<<dim3(32, 32, NB), 256, 0, stream>>>(qb, wkb, scores, denom);

    k_num<<<dim3(8, 32, NB), 256, 0, stream>>>(scores, vT, denom, out);
}

// Round 6
// 694.224 us; speedup vs baseline: 1.3324x; 1.0352x over previous
//
#include <hip/hip_runtime.h>

typedef unsigned short u16;
typedef unsigned int u32;

typedef __bf16 bf16x8 __attribute__((ext_vector_type(8)));
typedef float f32x4 __attribute__((ext_vector_type(4)));
typedef u16 u16x8 __attribute__((ext_vector_type(8)));

#define TSEQ 4096
#define DDIM 1024
#define NB 4
#define EPSV 1e-6f
// bounce-buffer row pitch in u16 (272 B = 17*16 -> rows stay 16B-aligned, banks rotate)
#define CPITCH 136

__device__ __forceinline__ u16 f2b(float f) {
    union { float f; u32 u; } v; v.f = f;
    u32 r = v.u + 0x7FFFu + ((v.u >> 16) & 1u);
    return (u16)(r >> 16);
}
__device__ __forceinline__ float b2f(u16 h) {
    union { u32 u; float f; } v; v.u = ((u32)h) << 16; return v.f;
}

// ---------------- merged prep: x->bf16, W->bf16 concat, bias concat ----------------
__global__ void k_prep(const float* __restrict__ x,
                       const float* __restrict__ wq, const float* __restrict__ wk,
                       const float* __restrict__ wv, const float* __restrict__ wa,
                       const float* __restrict__ bq, const float* __restrict__ bk,
                       const float* __restrict__ bv, const float* __restrict__ ba,
                       u16* __restrict__ xw, u16* __restrict__ wcat, float* __restrict__ bcat) {
    int bid = blockIdx.x;
    if (bid < 16384) {
        size_t i = ((size_t)bid * 256 + threadIdx.x) * 4;
        float4 f = *(const float4*)(x + i);
        ushort4 u;
        u.x = f2b(f.x); u.y = f2b(f.y); u.z = f2b(f.z); u.w = f2b(f.w);
        *(ushort4*)(xw + i) = u;
    } else if (bid < 20480) {
        size_t i = ((size_t)(bid - 16384) * 256 + threadIdx.x) * 4;
        int sel = (int)(i >> 20);
        const float* src = (sel == 0) ? wq : (sel == 1) ? wk : (sel == 2) ? wv : wa;
        size_t loc = i & ((1u << 20) - 1);
        float4 f = *(const float4*)(src + loc);
        ushort4 u;
        u.x = f2b(f.x); u.y = f2b(f.y); u.z = f2b(f.z); u.w = f2b(f.w);
        *(ushort4*)(wcat + i) = u;
    } else {
#pragma unroll
        for (int c = 0; c < 16; ++c) {
            int j = c * 256 + threadIdx.x;
            int sel = j >> 10;
            const float* src = (sel == 0) ? bq : (sel == 1) ? bk : (sel == 2) ? bv : ba;
            bcat[j] = src[j & 1023];
        }
    }
}

// ---------------- GEMM core helpers ----------------
// Async-stage a 128x64 bf16 tile into LDS with XOR bank swizzle (see round 3).
__device__ __forceinline__ void stage_async(u16* __restrict__ dst, const u16* __restrict__ src,
                                            int row0, int k0, int ld, int wid, int lane) {
#pragma unroll
    for (int c = 0; c < 4; ++c) {
        int rbase = wid * 32 + c * 8;
        int r = rbase + (lane >> 3);
        int hs = (lane & 7) ^ (r & 7);      // swizzled source granule
        const char* g = (const char*)src + ((size_t)(row0 + r) * ld + k0) * 2 + hs * 16;
        char* l = (char*)dst + rbase * 128 + lane * 16;
        __builtin_amdgcn_global_load_lds((const __attribute__((address_space(1))) u32*)g,
                                         (__attribute__((address_space(3))) u32*)l, 16, 0, 0);
    }
}

// One BK=64 MFMA step; un-swizzles fragment reads.
__device__ __forceinline__ void mma_tile(const u16* __restrict__ As, const u16* __restrict__ Bs,
                                         f32x4 acc[4][4], int wm, int wn, int quad, int l15) {
#pragma unroll
    for (int kk = 0; kk < 64; kk += 32) {
        int cg = (kk >> 3) + quad;
        bf16x8 a[4], b[4];
#pragma unroll
        for (int i = 0; i < 4; ++i) {
            int arow = wm * 64 + i * 16 + l15;
            int brow = wn * 64 + i * 16 + l15;
            a[i] = *(const bf16x8*)(As + arow * 64 + ((cg ^ (arow & 7)) << 3));
            b[i] = *(const bf16x8*)(Bs + brow * 64 + ((cg ^ (brow & 7)) << 3));
        }
#pragma unroll
        for (int i = 0; i < 4; ++i)
#pragma unroll
            for (int j = 0; j < 4; ++j)
                acc[i][j] = __builtin_amdgcn_mfma_f32_16x16x32_bf16(a[i], b[j], acc[i][j], 0, 0, 0);
    }
}

// ---------------- fused QKVA projection GEMM ----------------
// n-tile -> output is block-uniform: x 0-7 q, 8-15 k, 16-23 v (written transposed
// into vT), 24-31 gA (f32 log-sigmoid) + fused per-chunk column partial sums
// (feeds the gate scan directly; replaces the old k_scan_part 256MB re-read).
__global__ __launch_bounds__(256) void k_gemm_qkva(
    const u16* __restrict__ xw, const u16* __restrict__ wcat, const float* __restrict__ bcat,
    u16* __restrict__ qb, u16* __restrict__ kb, u16* __restrict__ vT, float* __restrict__ gA,
    float* __restrict__ part) {
    __shared__ __align__(16) char smem[CPITCH * 128 * 2];  // staging (32KB) U bf16 bounce (34KB)
    u16* As = (u16*)smem;
    u16* Bs = (u16*)(smem + 16384);
    int tid = threadIdx.x;
    int m0 = blockIdx.y * 128, n0 = blockIdx.x * 128;
    int wid = tid >> 6, lane = tid & 63;
    int wm = wid >> 1, wn = wid & 1, quad = lane >> 4, l15 = lane & 15;
    f32x4 acc[4][4] = {};
    for (int k0 = 0; k0 < DDIM; k0 += 64) {
        stage_async(As, xw, m0, k0, DDIM, wid, lane);
        stage_async(Bs, wcat, n0, k0, DDIM, wid, lane);
        __syncthreads();
        mma_tile(As, Bs, acc, wm, wn, quad, l15);
        __syncthreads();
    }
    int blk = n0 >> 10, nf0 = n0 & 1023;
    if (blk < 3) {
        // bf16 outputs: bounce through LDS, store vectorized.
        u16* Cs = (u16*)smem;
#pragma unroll
        for (int im = 0; im < 4; ++im)
#pragma unroll
        for (int jn = 0; jn < 4; ++jn) {
            float bias = bcat[n0 + wn * 64 + jn * 16 + l15];
#pragma unroll
            for (int r = 0; r < 4; ++r) {
                float z = acc[im][jn][r] + bias;
                if (blk < 2) z = fmaxf(z, 0.f);
                Cs[(wm * 64 + im * 16 + quad * 4 + r) * CPITCH + wn * 64 + jn * 16 + l15] = f2b(z);
            }
        }
        __syncthreads();
        if (blk < 2) {
            u16* dst = (blk == 0) ? qb : kb;
            int r = tid >> 1, ch = (tid & 1) * 64;
            size_t rowo = (size_t)(m0 + r) * DDIM + nf0 + ch;
#pragma unroll
            for (int i = 0; i < 8; ++i)
                *(u16x8*)(dst + rowo + i * 8) = *(const u16x8*)(Cs + r * CPITCH + ch + i * 8);
        } else {
            // v: read bounce transposed, write vT[b][j][t] coalesced.
            int j = tid >> 1, th = (tid & 1) * 64;
            int bB = m0 >> 12, t0m = m0 & 4095;
            size_t rowo = (((size_t)(bB * DDIM + nf0 + j)) << 12) + t0m + th;
#pragma unroll
            for (int i = 0; i < 8; ++i) {
                u16x8 vv;
#pragma unroll
                for (int e = 0; e < 8; ++e)
                    vv[e] = Cs[(th + i * 8 + e) * CPITCH + j];
                *(u16x8*)(vT + rowo + i * 8) = vv;
            }
        }
    } else {
        // gA: f32 stores (64B-coalesced) + fused per-chunk (64-row) column sums.
        // Wave (wm,wn) covers rows wm*64..wm*64+63 == scan-chunk cbase+wm exactly.
        int bB = m0 >> 12;
        int cbase = (m0 & 4095) >> 6;  // even; chunk = cbase + wm
#pragma unroll
        for (int jn = 0; jn < 4; ++jn) {
            int n = n0 + wn * 64 + jn * 16 + l15;
            float bias = bcat[n];
            int nf = n & 1023;
            float csum = 0.f;
#pragma unroll
            for (int im = 0; im < 4; ++im)
#pragma unroll
            for (int r = 0; r < 4; ++r) {
                int m = m0 + wm * 64 + im * 16 + quad * 4 + r;
                float z = acc[im][jn][r] + bias;
                float g = __logf(1.f / (1.f + __expf(-z)) + 1e-6f);
                gA[(size_t)m * DDIM + nf] = g;
                csum += g;
            }
            // reduce over quad (lanes l15, 16+l15, 32+l15, 48+l15)
            csum += __shfl_xor(csum, 16, 64);
            csum += __shfl_xor(csum, 32, 64);
            if (quad == 0)
                part[((size_t)(bB * 64 + cbase + wm) << 10) + nf] = csum;
        }
    }
}

// ---------------- gate scan sweep: exclusive suffix-sum of chunk partials ----------------
// One thread per (b, col). 64 independent loads fill regs (single vmcnt wait),
// then serial suffix sum in-register, write back. Replaces the 64-step dependent
// global r/w chain (latency-bound) of the old version.
__global__ __launch_bounds__(256) void k_scan_sweep(float* __restrict__ part) {
    int col = blockIdx.x * 256 + threadIdx.x;  // 0..1023
    int b = blockIdx.y;
    float v[64];
#pragma unroll
    for (int c = 0; c < 64; ++c)
        v[c] = part[((size_t)(b * 64 + c) << 10) + col];
    float run = 0.f;
#pragma unroll
    for (int c = 63; c >= 0; --c) {
        float t = v[c];
        part[((size_t)(b * 64 + c) << 10) + col] = run;
        run += t;
    }
}

__global__ void k_scan_apply(const float* __restrict__ gA, const float* __restrict__ part,
                             u16* __restrict__ kb) {
    int c = blockIdx.x, b = blockIdx.y, tid = threadIdx.x;
    const float* p = part + ((size_t)(b * 64 + c) << 10);
    float r0 = p[tid], r1 = p[tid + 256], r2 = p[tid + 512], r3 = p[tid + 768];
    size_t base = ((size_t)(b * TSEQ + c * 64)) << 10;
    for (int s = 63; s >= 0; --s) {
        size_t ro = base + ((size_t)s << 10);
        r0 += gA[ro + tid];
        kb[ro + tid] = f2b(b2f(kb[ro + tid]) * __expf(r0));
        r1 += gA[ro + tid + 256];
        kb[ro + tid + 256] = f2b(b2f(kb[ro + tid + 256]) * __expf(r1));
        r2 += gA[ro + tid + 512];
        kb[ro + tid + 512] = f2b(b2f(kb[ro + tid + 512]) * __expf(r2));
        r3 += gA[ro + tid + 768];
        kb[ro + tid + 768] = f2b(b2f(kb[ro + tid + 768]) * __expf(r3));
    }
}

// ---------------- scores = q @ wk^T (causal), bf16 out + denom atomics ----------------
__global__ __launch_bounds__(256) void k_scores(
    const u16* __restrict__ qb, const u16* __restrict__ wkb,
    u16* __restrict__ scores, float* __restrict__ denom) {
    int si = blockIdx.x, ti = blockIdx.y, b = blockIdx.z;
    if (si > ti) return;
    __shared__ __align__(16) char smem[CPITCH * 128 * 2];
    u16* As = (u16*)smem;
    u16* Bs = (u16*)(smem + 16384);
    int tid = threadIdx.x;
    const u16* A = qb + ((size_t)b << 22);
    const u16* Bm = wkb + ((size_t)b << 22);
    int t0 = ti * 128, s0 = si * 128;
    int wid = tid >> 6, lane = tid & 63;
    int wm = wid >> 1, wn = wid & 1, quad = lane >> 4, l15 = lane & 15;
    f32x4 acc[4][4] = {};
    for (int k0 = 0; k0 < DDIM; k0 += 64) {
        stage_async(As, A, t0, k0, DDIM, wid, lane);
        stage_async(Bs, Bm, s0, k0, DDIM, wid, lane);
        __syncthreads();
        mma_tile(As, Bs, acc, wm, wn, quad, l15);
        __syncthreads();
    }
    u16* Cs = (u16*)smem;
#pragma unroll
    for (int im = 0; im < 4; ++im) {
#pragma unroll
        for (int r = 0; r < 4; ++r) {
            int trow = t0 + wm * 64 + im * 16 + quad * 4 + r;
            float rs = 0.f;
#pragma unroll
            for (int jn = 0; jn < 4; ++jn) {
                int s = s0 + wn * 64 + jn * 16 + l15;
                float val = acc[im][jn][r];
                if (s > trow) val = 0.f;
                rs += val;
                Cs[(wm * 64 + im * 16 + quad * 4 + r) * CPITCH + wn * 64 + jn * 16 + l15] = f2b(val);
            }
#pragma unroll
            for (int m = 1; m < 16; m <<= 1) rs += __shfl_xor(rs, m, 64);
            if (l15 == 0) atomicAdd(denom + (b << 12) + trow, rs);
        }
    }
    __syncthreads();
    int r = tid >> 1, ch = (tid & 1) * 64;
    size_t rowo = ((size_t)(b * TSEQ + t0 + r) << 12) + s0 + ch;
#pragma unroll
    for (int i = 0; i < 8; ++i)
        *(u16x8*)(scores + rowo + i * 8) = *(const u16x8*)(Cs + r * CPITCH + ch + i * 8);
}

// ---------------- num = scores @ v (causal K bound), divide by denom ----------------
__global__ __launch_bounds__(256) void k_num(
    const u16* __restrict__ scores, const u16* __restrict__ vT,
    const float* __restrict__ denom, float* __restrict__ out) {
    int ji = blockIdx.x, ti = blockIdx.y, b = blockIdx.z;
    __shared__ __align__(16) u16 As[128 * 64];
    __shared__ __align__(16) u16 Bs[128 * 64];
    int tid = threadIdx.x;
    const u16* A = scores + ((size_t)b << 24);  // [T][T]
    const u16* Bm = vT + ((size_t)b << 22);     // [D][T]
    int t0 = ti * 128, j0 = ji * 128;
    int wid = tid >> 6, lane = tid & 63;
    int wm = wid >> 1, wn = wid & 1, quad = lane >> 4, l15 = lane & 15;
    f32x4 acc[4][4] = {};
    int kmax = (ti + 1) * 128;
    for (int k0 = 0; k0 < kmax; k0 += 64) {
        stage_async(As, A, t0, k0, TSEQ, wid, lane);
        stage_async(Bs, Bm, j0, k0, TSEQ, wid, lane);
        __syncthreads();
        mma_tile(As, Bs, acc, wm, wn, quad, l15);
        __syncthreads();
    }
#pragma unroll
    for (int im = 0; im < 4; ++im) {
#pragma unroll
        for (int r = 0; r < 4; ++r) {
            int t = t0 + wm * 64 + im * 16 + quad * 4 + r;
            float den = denom[(b << 12) + t] + EPSV;
#pragma unroll
            for (int jn = 0; jn < 4; ++jn) {
                int j = j0 + wn * 64 + jn * 16 + l15;
                out[((size_t)(b * TSEQ + t) << 10) + j] = acc[im][jn][r] / den;
            }
        }
    }
}

// ---------------- workspace layout (bytes) ----------------
static const size_t OFF_Q      = 0;
static const size_t OFF_WK     = 33554432;
static const size_t OFF_VT     = 67108864;
static const size_t OFF_DENOM  = 100663296;
static const size_t OFF_BCAT   = 100728832;
static const size_t OFF_XW     = 100745216;
static const size_t OFF_WCAT   = 134299648;
static const size_t OFF_GA     = 176242688;
static const size_t OFF_PART   = 243351552;
static const size_t OFF_SCORES = OFF_XW;  // 134,217,728 B, overlays dead early region

extern "C" void kernel_launch(void* const* d_in, const int* in_sizes, int n_in,
                              void* d_out, int out_size, void* d_ws, size_t ws_size,
                              hipStream_t stream) {
    const float* x  = (const float*)d_in[0];
    const float* Wq = (const float*)d_in[1];
    const float* bq = (const float*)d_in[2];
    const float* Wk = (const float*)d_in[3];
    const float* bk = (const float*)d_in[4];
    const float* Wv = (const float*)d_in[5];
    const float* bv = (const float*)d_in[6];
    const float* Wa = (const float*)d_in[7];
    const float* ba = (const float*)d_in[8];
    float* out = (float*)d_out;

    char* W = (char*)d_ws;
    u16* qb      = (u16*)(W + OFF_Q);
    u16* wkb     = (u16*)(W + OFF_WK);
    u16* vT      = (u16*)(W + OFF_VT);
    float* denom = (float*)(W + OFF_DENOM);
    float* bcat  = (float*)(W + OFF_BCAT);
    u16* xw      = (u16*)(W + OFF_XW);
    u16* wcat    = (u16*)(W + OFF_WCAT);
    float* gA    = (float*)(W + OFF_GA);
    float* part  = (float*)(W + OFF_PART);
    u16* scores  = (u16*)(W + OFF_SCORES);

    hipMemsetAsync(denom, 0, (size_t)NB * TSEQ * sizeof(float), stream);

    k_prep<<<20481, 256, 0, stream>>>(x, Wq, Wk, Wv, Wa, bq, bk, bv, ba, xw, wcat, bcat);

    k_gemm_qkva<<<dim3(32, 128), 256, 0, stream>>>(xw, wcat, bcat, qb, wkb, vT, gA, part);

    k_scan_sweep<<<dim3(4, NB), 256, 0, stream>>>(part);
    k_scan_apply<<<dim3(64, NB), 256, 0, stream>>>(gA, part, wkb);

    k_scores<<<dim3(32, 32, NB), 256, 0, stream>>>(qb, wkb, scores, denom);

    k_num<<<dim3(8, 32, NB), 256, 0, stream>>>(scores, vT, denom, out);
}

// Round 7
// 637.879 us; speedup vs baseline: 1.4501x; 1.0883x over previous
//
#include <hip/hip_runtime.h>

typedef unsigned short u16;
typedef unsigned int u32;

typedef __bf16 bf16x8 __attribute__((ext_vector_type(8)));
typedef float f32x4 __attribute__((ext_vector_type(4)));
typedef u16 u16x8 __attribute__((ext_vector_type(8)));

#define TSEQ 4096
#define DDIM 1024
#define NB 4
#define EPSV 1e-6f
// bounce-buffer row pitch in u16 (272 B = 17*16 -> rows stay 16B-aligned, banks rotate)
#define CPITCH 136

__device__ __forceinline__ u16 f2b(float f) {
    union { float f; u32 u; } v; v.f = f;
    u32 r = v.u + 0x7FFFu + ((v.u >> 16) & 1u);
    return (u16)(r >> 16);
}
__device__ __forceinline__ float b2f(u16 h) {
    union { u32 u; float f; } v; v.u = ((u32)h) << 16; return v.f;
}

// ---------------- merged prep: x->bf16, W->bf16 concat, bias concat ----------------
// Grid-stride, 16 float4 per thread: deep ILP, coalesced, few blocks.
__global__ __launch_bounds__(256) void k_prep(
    const float* __restrict__ x,
    const float* __restrict__ wq, const float* __restrict__ wk,
    const float* __restrict__ wv, const float* __restrict__ wa,
    const float* __restrict__ bq, const float* __restrict__ bk,
    const float* __restrict__ bv, const float* __restrict__ ba,
    u16* __restrict__ xw, u16* __restrict__ wcat, float* __restrict__ bcat) {
    int bid = blockIdx.x, tid = threadIdx.x;
    if (bid < 1024) {
        // x: 4.19M float4, 1024 blocks x 256 thr x 16
        size_t base = (size_t)bid * 4096 + tid;
#pragma unroll
        for (int k = 0; k < 16; ++k) {
            size_t f4 = base + k * 256;
            float4 f = ((const float4*)x)[f4];
            ushort4 u;
            u.x = f2b(f.x); u.y = f2b(f.y); u.z = f2b(f.z); u.w = f2b(f.w);
            *(ushort4*)(xw + f4 * 4) = u;
        }
    } else if (bid < 1280) {
        // W: 1.05M float4, 256 blocks x 256 thr x 16; each W is 262144 float4
        size_t base = (size_t)(bid - 1024) * 4096 + tid;
#pragma unroll
        for (int k = 0; k < 16; ++k) {
            size_t f4 = base + k * 256;
            int sel = (int)(f4 >> 18);
            const float* src = (sel == 0) ? wq : (sel == 1) ? wk : (sel == 2) ? wv : wa;
            float4 f = ((const float4*)src)[f4 & 262143];
            ushort4 u;
            u.x = f2b(f.x); u.y = f2b(f.y); u.z = f2b(f.z); u.w = f2b(f.w);
            *(ushort4*)(wcat + f4 * 4) = u;
        }
    } else {
#pragma unroll
        for (int c = 0; c < 16; ++c) {
            int j = c * 256 + tid;
            int sel = j >> 10;
            const float* src = (sel == 0) ? bq : (sel == 1) ? bk : (sel == 2) ? bv : ba;
            bcat[j] = src[j & 1023];
        }
    }
}

// ---------------- GEMM core helpers ----------------
// Async-stage a 128x64 bf16 tile into LDS with XOR bank swizzle (see round 3).
__device__ __forceinline__ void stage_async(u16* __restrict__ dst, const u16* __restrict__ src,
                                            int row0, int k0, int ld, int wid, int lane) {
#pragma unroll
    for (int c = 0; c < 4; ++c) {
        int rbase = wid * 32 + c * 8;
        int r = rbase + (lane >> 3);
        int hs = (lane & 7) ^ (r & 7);      // swizzled source granule
        const char* g = (const char*)src + ((size_t)(row0 + r) * ld + k0) * 2 + hs * 16;
        char* l = (char*)dst + rbase * 128 + lane * 16;
        __builtin_amdgcn_global_load_lds((const __attribute__((address_space(1))) u32*)g,
                                         (__attribute__((address_space(3))) u32*)l, 16, 0, 0);
    }
}

// One BK=64 MFMA step; un-swizzles fragment reads.
__device__ __forceinline__ void mma_tile(const u16* __restrict__ As, const u16* __restrict__ Bs,
                                         f32x4 acc[4][4], int wm, int wn, int quad, int l15) {
#pragma unroll
    for (int kk = 0; kk < 64; kk += 32) {
        int cg = (kk >> 3) + quad;
        bf16x8 a[4], b[4];
#pragma unroll
        for (int i = 0; i < 4; ++i) {
            int arow = wm * 64 + i * 16 + l15;
            int brow = wn * 64 + i * 16 + l15;
            a[i] = *(const bf16x8*)(As + arow * 64 + ((cg ^ (arow & 7)) << 3));
            b[i] = *(const bf16x8*)(Bs + brow * 64 + ((cg ^ (brow & 7)) << 3));
        }
#pragma unroll
        for (int i = 0; i < 4; ++i)
#pragma unroll
            for (int j = 0; j < 4; ++j)
                acc[i][j] = __builtin_amdgcn_mfma_f32_16x16x32_bf16(a[i], b[j], acc[i][j], 0, 0, 0);
    }
}

// ---------------- fused QKVA projection GEMM ----------------
// n-tile -> output is block-uniform: x 0-7 q, 8-15 k, 16-23 v (written transposed
// into vT), 24-31 gA (f32 log-sigmoid) + fused per-chunk column partial sums
// (raw chunk sums; consumed directly by k_scan_apply's fused suffix-sum).
__global__ __launch_bounds__(256) void k_gemm_qkva(
    const u16* __restrict__ xw, const u16* __restrict__ wcat, const float* __restrict__ bcat,
    u16* __restrict__ qb, u16* __restrict__ kb, u16* __restrict__ vT, float* __restrict__ gA,
    float* __restrict__ part) {
    __shared__ __align__(16) char smem[CPITCH * 128 * 2];  // staging (32KB) U bf16 bounce (34KB)
    u16* As = (u16*)smem;
    u16* Bs = (u16*)(smem + 16384);
    int tid = threadIdx.x;
    int m0 = blockIdx.y * 128, n0 = blockIdx.x * 128;
    int wid = tid >> 6, lane = tid & 63;
    int wm = wid >> 1, wn = wid & 1, quad = lane >> 4, l15 = lane & 15;
    f32x4 acc[4][4] = {};
    for (int k0 = 0; k0 < DDIM; k0 += 64) {
        stage_async(As, xw, m0, k0, DDIM, wid, lane);
        stage_async(Bs, wcat, n0, k0, DDIM, wid, lane);
        __syncthreads();
        mma_tile(As, Bs, acc, wm, wn, quad, l15);
        __syncthreads();
    }
    int blk = n0 >> 10, nf0 = n0 & 1023;
    if (blk < 3) {
        // bf16 outputs: bounce through LDS, store vectorized.
        u16* Cs = (u16*)smem;
#pragma unroll
        for (int im = 0; im < 4; ++im)
#pragma unroll
        for (int jn = 0; jn < 4; ++jn) {
            float bias = bcat[n0 + wn * 64 + jn * 16 + l15];
#pragma unroll
            for (int r = 0; r < 4; ++r) {
                float z = acc[im][jn][r] + bias;
                if (blk < 2) z = fmaxf(z, 0.f);
                Cs[(wm * 64 + im * 16 + quad * 4 + r) * CPITCH + wn * 64 + jn * 16 + l15] = f2b(z);
            }
        }
        __syncthreads();
        if (blk < 2) {
            u16* dst = (blk == 0) ? qb : kb;
            int r = tid >> 1, ch = (tid & 1) * 64;
            size_t rowo = (size_t)(m0 + r) * DDIM + nf0 + ch;
#pragma unroll
            for (int i = 0; i < 8; ++i)
                *(u16x8*)(dst + rowo + i * 8) = *(const u16x8*)(Cs + r * CPITCH + ch + i * 8);
        } else {
            // v: read bounce transposed, write vT[b][j][t] coalesced.
            int j = tid >> 1, th = (tid & 1) * 64;
            int bB = m0 >> 12, t0m = m0 & 4095;
            size_t rowo = (((size_t)(bB * DDIM + nf0 + j)) << 12) + t0m + th;
#pragma unroll
            for (int i = 0; i < 8; ++i) {
                u16x8 vv;
#pragma unroll
                for (int e = 0; e < 8; ++e)
                    vv[e] = Cs[(th + i * 8 + e) * CPITCH + j];
                *(u16x8*)(vT + rowo + i * 8) = vv;
            }
        }
    } else {
        // gA: f32 stores (64B-coalesced) + fused per-chunk (64-row) column sums.
        int bB = m0 >> 12;
        int cbase = (m0 & 4095) >> 6;  // even; chunk = cbase + wm
#pragma unroll
        for (int jn = 0; jn < 4; ++jn) {
            int n = n0 + wn * 64 + jn * 16 + l15;
            float bias = bcat[n];
            int nf = n & 1023;
            float csum = 0.f;
#pragma unroll
            for (int im = 0; im < 4; ++im)
#pragma unroll
            for (int r = 0; r < 4; ++r) {
                int m = m0 + wm * 64 + im * 16 + quad * 4 + r;
                float z = acc[im][jn][r] + bias;
                float g = __logf(1.f / (1.f + __expf(-z)) + 1e-6f);
                gA[(size_t)m * DDIM + nf] = g;
                csum += g;
            }
            csum += __shfl_xor(csum, 16, 64);
            csum += __shfl_xor(csum, 32, 64);
            if (quad == 0)
                part[((size_t)(bB * 64 + cbase + wm) << 10) + nf] = csum;
        }
    }
}

// ---------------- gate scan apply (fused suffix-sum of raw chunk partials) ----------------
// One column per thread; grid (chunk, b, colchunk) = 1024 blocks -> 4 blocks/CU
// (the old 256-block version had 1 block/CU: latency-starved).
__global__ __launch_bounds__(256) void k_scan_apply(
    const float* __restrict__ gA, const float* __restrict__ part, u16* __restrict__ kb) {
    int c = blockIdx.x, b = blockIdx.y;
    int col = blockIdx.z * 256 + threadIdx.x;
    float r = 0.f;
    for (int c2 = c + 1; c2 < 64; ++c2)
        r += part[((size_t)(b * 64 + c2) << 10) + col];
    size_t base = (((size_t)(b * TSEQ + c * 64)) << 10) + col;
#pragma unroll 4
    for (int s = 63; s >= 0; --s) {
        size_t ro = base + ((size_t)s << 10);
        r += gA[ro];
        kb[ro] = f2b(b2f(kb[ro]) * __expf(r));
    }
}

// ---------------- scores = q @ wk^T (causal), bf16 out + denom atomics ----------------
// Triangular 1D grid: 528 blocks per batch, si fastest (consecutive blocks share
// the q A-tile -> L2 locality); no dead blocks.
__global__ __launch_bounds__(256) void k_scores(
    const u16* __restrict__ qb, const u16* __restrict__ wkb,
    u16* __restrict__ scores, float* __restrict__ denom) {
    int li = blockIdx.x, b = blockIdx.y;
    int ti = (int)((sqrtf(8.f * li + 1.f) - 1.f) * 0.5f);
    while ((ti + 1) * (ti + 2) / 2 <= li) ++ti;
    while (ti * (ti + 1) / 2 > li) --ti;
    int si = li - ti * (ti + 1) / 2;
    __shared__ __align__(16) char smem[CPITCH * 128 * 2];
    u16* As = (u16*)smem;
    u16* Bs = (u16*)(smem + 16384);
    int tid = threadIdx.x;
    const u16* A = qb + ((size_t)b << 22);
    const u16* Bm = wkb + ((size_t)b << 22);
    int t0 = ti * 128, s0 = si * 128;
    int wid = tid >> 6, lane = tid & 63;
    int wm = wid >> 1, wn = wid & 1, quad = lane >> 4, l15 = lane & 15;
    f32x4 acc[4][4] = {};
    for (int k0 = 0; k0 < DDIM; k0 += 64) {
        stage_async(As, A, t0, k0, DDIM, wid, lane);
        stage_async(Bs, Bm, s0, k0, DDIM, wid, lane);
        __syncthreads();
        mma_tile(As, Bs, acc, wm, wn, quad, l15);
        __syncthreads();
    }
    u16* Cs = (u16*)smem;
#pragma unroll
    for (int im = 0; im < 4; ++im) {
#pragma unroll
        for (int r = 0; r < 4; ++r) {
            int trow = t0 + wm * 64 + im * 16 + quad * 4 + r;
            float rs = 0.f;
#pragma unroll
            for (int jn = 0; jn < 4; ++jn) {
                int s = s0 + wn * 64 + jn * 16 + l15;
                float val = acc[im][jn][r];
                if (s > trow) val = 0.f;
                rs += val;
                Cs[(wm * 64 + im * 16 + quad * 4 + r) * CPITCH + wn * 64 + jn * 16 + l15] = f2b(val);
            }
#pragma unroll
            for (int m = 1; m < 16; m <<= 1) rs += __shfl_xor(rs, m, 64);
            if (l15 == 0) atomicAdd(denom + (b << 12) + trow, rs);
        }
    }
    __syncthreads();
    int r = tid >> 1, ch = (tid & 1) * 64;
    size_t rowo = ((size_t)(b * TSEQ + t0 + r) << 12) + s0 + ch;
#pragma unroll
    for (int i = 0; i < 8; ++i)
        *(u16x8*)(scores + rowo + i * 8) = *(const u16x8*)(Cs + r * CPITCH + ch + i * 8);
}

// ---------------- num = scores @ v (causal K bound), divide by denom ----------------
// ti reversed: longest blocks (most K-iters) dispatch first -> better tail.
__global__ __launch_bounds__(256) void k_num(
    const u16* __restrict__ scores, const u16* __restrict__ vT,
    const float* __restrict__ denom, float* __restrict__ out) {
    int ji = blockIdx.x, ti = 31 - blockIdx.y, b = blockIdx.z;
    __shared__ __align__(16) u16 As[128 * 64];
    __shared__ __align__(16) u16 Bs[128 * 64];
    int tid = threadIdx.x;
    const u16* A = scores + ((size_t)b << 24);  // [T][T]
    const u16* Bm = vT + ((size_t)b << 22);     // [D][T]
    int t0 = ti * 128, j0 = ji * 128;
    int wid = tid >> 6, lane = tid & 63;
    int wm = wid >> 1, wn = wid & 1, quad = lane >> 4, l15 = lane & 15;
    f32x4 acc[4][4] = {};
    int kmax = (ti + 1) * 128;
    for (int k0 = 0; k0 < kmax; k0 += 64) {
        stage_async(As, A, t0, k0, TSEQ, wid, lane);
        stage_async(Bs, Bm, j0, k0, TSEQ, wid, lane);
        __syncthreads();
        mma_tile(As, Bs, acc, wm, wn, quad, l15);
        __syncthreads();
    }
#pragma unroll
    for (int im = 0; im < 4; ++im) {
#pragma unroll
        for (int r = 0; r < 4; ++r) {
            int t = t0 + wm * 64 + im * 16 + quad * 4 + r;
            float den = denom[(b << 12) + t] + EPSV;
#pragma unroll
            for (int jn = 0; jn < 4; ++jn) {
                int j = j0 + wn * 64 + jn * 16 + l15;
                out[((size_t)(b * TSEQ + t) << 10) + j] = acc[im][jn][r] / den;
            }
        }
    }
}

// ---------------- workspace layout (bytes) ----------------
static const size_t OFF_Q      = 0;
static const size_t OFF_WK     = 33554432;
static const size_t OFF_VT     = 67108864;
static const size_t OFF_DENOM  = 100663296;
static const size_t OFF_BCAT   = 100728832;
static const size_t OFF_XW     = 100745216;
static const size_t OFF_WCAT   = 134299648;
static const size_t OFF_GA     = 176242688;
static const size_t OFF_PART   = 243351552;
static const size_t OFF_SCORES = OFF_XW;  // 134,217,728 B, overlays dead early region

extern "C" void kernel_launch(void* const* d_in, const int* in_sizes, int n_in,
                              void* d_out, int out_size, void* d_ws, size_t ws_size,
                              hipStream_t stream) {
    const float* x  = (const float*)d_in[0];
    const float* Wq = (const float*)d_in[1];
    const float* bq = (const float*)d_in[2];
    const float* Wk = (const float*)d_in[3];
    const float* bk = (const float*)d_in[4];
    const float* Wv = (const float*)d_in[5];
    const float* bv = (const float*)d_in[6];
    const float* Wa = (const float*)d_in[7];
    const float* ba = (const float*)d_in[8];
    float* out = (float*)d_out;

    char* W = (char*)d_ws;
    u16* qb      = (u16*)(W + OFF_Q);
    u16* wkb     = (u16*)(W + OFF_WK);
    u16* vT      = (u16*)(W + OFF_VT);
    float* denom = (float*)(W + OFF_DENOM);
    float* bcat  = (float*)(W + OFF_BCAT);
    u16* xw      = (u16*)(W + OFF_XW);
    u16* wcat    = (u16*)(W + OFF_WCAT);
    float* gA    = (float*)(W + OFF_GA);
    float* part  = (float*)(W + OFF_PART);
    u16* scores  = (u16*)(W + OFF_SCORES);

    hipMemsetAsync(denom, 0, (size_t)NB * TSEQ * sizeof(float), stream);

    k_prep<<<1281, 256, 0, stream>>>(x, Wq, Wk, Wv, Wa, bq, bk, bv, ba, xw, wcat, bcat);

    k_gemm_qkva<<<dim3(32, 128), 256, 0, stream>>>(xw, wcat, bcat, qb, wkb, vT, gA, part);

    k_scan_apply<<<dim3(64, NB, 4), 256, 0, stream>>>(gA, part, wkb);

    k_scores<<<dim3(528, NB), 256, 0, stream>>>(qb, wkb, scores, denom);

    k_num<<<dim3(8, 32, NB), 256, 0, stream>>>(scores, vT, denom, out);
}

// Round 8
// 626.636 us; speedup vs baseline: 1.4761x; 1.0179x over previous
//
#include <hip/hip_runtime.h>

typedef unsigned short u16;
typedef unsigned int u32;

typedef __bf16 bf16x8 __attribute__((ext_vector_type(8)));
typedef float f32x4 __attribute__((ext_vector_type(4)));
typedef u16 u16x8 __attribute__((ext_vector_type(8)));

#define TSEQ 4096
#define DDIM 1024
#define NB 4
#define EPSV 1e-6f
// bounce-buffer row pitch in u16 (272 B = 17*16 -> rows stay 16B-aligned, banks rotate)
#define CPITCH 136

__device__ __forceinline__ u16 f2b(float f) {
    union { float f; u32 u; } v; v.f = f;
    u32 r = v.u + 0x7FFFu + ((v.u >> 16) & 1u);
    return (u16)(r >> 16);
}
__device__ __forceinline__ float b2f(u16 h) {
    union { u32 u; float f; } v; v.u = ((u32)h) << 16; return v.f;
}
__device__ __forceinline__ u16 f2h(float f) {
    union { _Float16 h; u16 u; } v; v.h = (_Float16)f; return v.u;
}
__device__ __forceinline__ float h2f(u16 u) {
    union { u16 u; _Float16 h; } v; v.u = u; return (float)v.h;
}

// ---------------- merged prep: x->bf16, W->bf16 concat, bias concat, denom zero ----
__global__ __launch_bounds__(256) void k_prep(
    const float* __restrict__ x,
    const float* __restrict__ wq, const float* __restrict__ wk,
    const float* __restrict__ wv, const float* __restrict__ wa,
    const float* __restrict__ bq, const float* __restrict__ bk,
    const float* __restrict__ bv, const float* __restrict__ ba,
    u16* __restrict__ xw, u16* __restrict__ wcat, float* __restrict__ bcat,
    float* __restrict__ denom) {
    int bid = blockIdx.x, tid = threadIdx.x;
    if (bid < 1024) {
        // x: 4.19M float4, 1024 blocks x 256 thr x 16
        size_t base = (size_t)bid * 4096 + tid;
#pragma unroll
        for (int k = 0; k < 16; ++k) {
            size_t f4 = base + k * 256;
            float4 f = ((const float4*)x)[f4];
            ushort4 u;
            u.x = f2b(f.x); u.y = f2b(f.y); u.z = f2b(f.z); u.w = f2b(f.w);
            *(ushort4*)(xw + f4 * 4) = u;
        }
    } else if (bid < 1280) {
        // W: 1.05M float4, 256 blocks x 256 thr x 16; each W is 262144 float4
        size_t base = (size_t)(bid - 1024) * 4096 + tid;
#pragma unroll
        for (int k = 0; k < 16; ++k) {
            size_t f4 = base + k * 256;
            int sel = (int)(f4 >> 18);
            const float* src = (sel == 0) ? wq : (sel == 1) ? wk : (sel == 2) ? wv : wa;
            float4 f = ((const float4*)src)[f4 & 262143];
            ushort4 u;
            u.x = f2b(f.x); u.y = f2b(f.y); u.z = f2b(f.z); u.w = f2b(f.w);
            *(ushort4*)(wcat + f4 * 4) = u;
        }
    } else if (bid == 1280) {
#pragma unroll
        for (int c = 0; c < 16; ++c) {
            int j = c * 256 + tid;
            int sel = j >> 10;
            const float* src = (sel == 0) ? bq : (sel == 1) ? bk : (sel == 2) ? bv : ba;
            bcat[j] = src[j & 1023];
        }
    } else {
        // denom zero: NB*TSEQ = 16384 floats = 4096 float4
        float4 z = {0.f, 0.f, 0.f, 0.f};
#pragma unroll
        for (int k = 0; k < 16; ++k)
            ((float4*)denom)[k * 256 + tid] = z;
    }
}

// ---------------- GEMM core helpers ----------------
// Async-stage a 128x64 bf16 tile into LDS with XOR bank swizzle (see round 3).
__device__ __forceinline__ void stage_async(u16* __restrict__ dst, const u16* __restrict__ src,
                                            int row0, int k0, int ld, int wid, int lane) {
#pragma unroll
    for (int c = 0; c < 4; ++c) {
        int rbase = wid * 32 + c * 8;
        int r = rbase + (lane >> 3);
        int hs = (lane & 7) ^ (r & 7);      // swizzled source granule
        const char* g = (const char*)src + ((size_t)(row0 + r) * ld + k0) * 2 + hs * 16;
        char* l = (char*)dst + rbase * 128 + lane * 16;
        __builtin_amdgcn_global_load_lds((const __attribute__((address_space(1))) u32*)g,
                                         (__attribute__((address_space(3))) u32*)l, 16, 0, 0);
    }
}

// One BK=64 MFMA step; un-swizzles fragment reads.
__device__ __forceinline__ void mma_tile(const u16* __restrict__ As, const u16* __restrict__ Bs,
                                         f32x4 acc[4][4], int wm, int wn, int quad, int l15) {
#pragma unroll
    for (int kk = 0; kk < 64; kk += 32) {
        int cg = (kk >> 3) + quad;
        bf16x8 a[4], b[4];
#pragma unroll
        for (int i = 0; i < 4; ++i) {
            int arow = wm * 64 + i * 16 + l15;
            int brow = wn * 64 + i * 16 + l15;
            a[i] = *(const bf16x8*)(As + arow * 64 + ((cg ^ (arow & 7)) << 3));
            b[i] = *(const bf16x8*)(Bs + brow * 64 + ((cg ^ (brow & 7)) << 3));
        }
#pragma unroll
        for (int i = 0; i < 4; ++i)
#pragma unroll
            for (int j = 0; j < 4; ++j)
                acc[i][j] = __builtin_amdgcn_mfma_f32_16x16x32_bf16(a[i], b[j], acc[i][j], 0, 0, 0);
    }
}

// ---------------- fused QKVA projection GEMM ----------------
// n-tile -> output is block-uniform: x 0-7 q, 8-15 k, 16-23 v (written transposed
// into vT), 24-31 gA (f16 log-sigmoid) + fused per-chunk column partial sums.
// All outputs bounce through LDS for vectorized 16B stores.
__global__ __launch_bounds__(256) void k_gemm_qkva(
    const u16* __restrict__ xw, const u16* __restrict__ wcat, const float* __restrict__ bcat,
    u16* __restrict__ qb, u16* __restrict__ kb, u16* __restrict__ vT, u16* __restrict__ gA,
    float* __restrict__ part) {
    __shared__ __align__(16) char smem[CPITCH * 128 * 2];  // staging (32KB) U bounce (34KB)
    u16* As = (u16*)smem;
    u16* Bs = (u16*)(smem + 16384);
    int tid = threadIdx.x;
    int m0 = blockIdx.y * 128, n0 = blockIdx.x * 128;
    int wid = tid >> 6, lane = tid & 63;
    int wm = wid >> 1, wn = wid & 1, quad = lane >> 4, l15 = lane & 15;
    f32x4 acc[4][4] = {};
    for (int k0 = 0; k0 < DDIM; k0 += 64) {
        stage_async(As, xw, m0, k0, DDIM, wid, lane);
        stage_async(Bs, wcat, n0, k0, DDIM, wid, lane);
        __syncthreads();
        mma_tile(As, Bs, acc, wm, wn, quad, l15);
        __syncthreads();
    }
    int blk = n0 >> 10, nf0 = n0 & 1023;
    u16* Cs = (u16*)smem;
    if (blk == 3) {
        // gA: f16 log-sigmoid into bounce + fused per-chunk (64-row) column sums.
        int bB = m0 >> 12;
        int cbase = (m0 & 4095) >> 6;  // even; chunk = cbase + wm
#pragma unroll
        for (int jn = 0; jn < 4; ++jn) {
            int col = wn * 64 + jn * 16 + l15;
            float bias = bcat[n0 + col];
            float csum = 0.f;
#pragma unroll
            for (int im = 0; im < 4; ++im)
#pragma unroll
            for (int r = 0; r < 4; ++r) {
                float z = acc[im][jn][r] + bias;
                float g = __logf(1.f / (1.f + __expf(-z)) + 1e-6f);
                Cs[(wm * 64 + im * 16 + quad * 4 + r) * CPITCH + col] = f2h(g);
                csum += g;
            }
            csum += __shfl_xor(csum, 16, 64);
            csum += __shfl_xor(csum, 32, 64);
            if (quad == 0)
                part[((size_t)(bB * 64 + cbase + wm) << 10) + nf0 + col] = csum;
        }
    } else {
#pragma unroll
        for (int im = 0; im < 4; ++im)
#pragma unroll
        for (int jn = 0; jn < 4; ++jn) {
            float bias = bcat[n0 + wn * 64 + jn * 16 + l15];
#pragma unroll
            for (int r = 0; r < 4; ++r) {
                float z = acc[im][jn][r] + bias;
                if (blk < 2) z = fmaxf(z, 0.f);
                Cs[(wm * 64 + im * 16 + quad * 4 + r) * CPITCH + wn * 64 + jn * 16 + l15] = f2b(z);
            }
        }
    }
    __syncthreads();
    if (blk == 2) {
        // v: read bounce transposed, write vT[b][j][t] coalesced.
        int j = tid >> 1, th = (tid & 1) * 64;
        int bB = m0 >> 12, t0m = m0 & 4095;
        size_t rowo = (((size_t)(bB * DDIM + nf0 + j)) << 12) + t0m + th;
#pragma unroll
        for (int i = 0; i < 8; ++i) {
            u16x8 vv;
#pragma unroll
            for (int e = 0; e < 8; ++e)
                vv[e] = Cs[(th + i * 8 + e) * CPITCH + j];
            *(u16x8*)(vT + rowo + i * 8) = vv;
        }
    } else {
        u16* dst = (blk == 0) ? qb : (blk == 1) ? kb : gA;
        int r = tid >> 1, ch = (tid & 1) * 64;
        size_t rowo = (size_t)(m0 + r) * DDIM + nf0 + ch;
#pragma unroll
        for (int i = 0; i < 8; ++i)
            *(u16x8*)(dst + rowo + i * 8) = *(const u16x8*)(Cs + r * CPITCH + ch + i * 8);
    }
}

// ---------------- gate scan apply (fused suffix-sum of raw chunk partials) ----------------
// One column per thread; grid (chunk, b, colchunk) = 1024 blocks -> 4 blocks/CU.
__global__ __launch_bounds__(256) void k_scan_apply(
    const u16* __restrict__ gA, const float* __restrict__ part, u16* __restrict__ kb) {
    int c = blockIdx.x, b = blockIdx.y;
    int col = blockIdx.z * 256 + threadIdx.x;
    float r = 0.f;
    for (int c2 = c + 1; c2 < 64; ++c2)
        r += part[((size_t)(b * 64 + c2) << 10) + col];
    size_t base = (((size_t)(b * TSEQ + c * 64)) << 10) + col;
#pragma unroll 4
    for (int s = 63; s >= 0; --s) {
        size_t ro = base + ((size_t)s << 10);
        r += h2f(gA[ro]);
        kb[ro] = f2b(b2f(kb[ro]) * __expf(r));
    }
}

// ---------------- scores = q @ wk^T (causal), bf16 out + denom atomics ----------------
// Triangular 1D grid: 528 blocks per batch, si fastest (L2 locality on q A-tile).
__global__ __launch_bounds__(256) void k_scores(
    const u16* __restrict__ qb, const u16* __restrict__ wkb,
    u16* __restrict__ scores, float* __restrict__ denom) {
    int li = blockIdx.x, b = blockIdx.y;
    int ti = (int)((sqrtf(8.f * li + 1.f) - 1.f) * 0.5f);
    while ((ti + 1) * (ti + 2) / 2 <= li) ++ti;
    while (ti * (ti + 1) / 2 > li) --ti;
    int si = li - ti * (ti + 1) / 2;
    __shared__ __align__(16) char smem[CPITCH * 128 * 2];
    u16* As = (u16*)smem;
    u16* Bs = (u16*)(smem + 16384);
    int tid = threadIdx.x;
    const u16* A = qb + ((size_t)b << 22);
    const u16* Bm = wkb + ((size_t)b << 22);
    int t0 = ti * 128, s0 = si * 128;
    int wid = tid >> 6, lane = tid & 63;
    int wm = wid >> 1, wn = wid & 1, quad = lane >> 4, l15 = lane & 15;
    f32x4 acc[4][4] = {};
    for (int k0 = 0; k0 < DDIM; k0 += 64) {
        stage_async(As, A, t0, k0, DDIM, wid, lane);
        stage_async(Bs, Bm, s0, k0, DDIM, wid, lane);
        __syncthreads();
        mma_tile(As, Bs, acc, wm, wn, quad, l15);
        __syncthreads();
    }
    u16* Cs = (u16*)smem;
#pragma unroll
    for (int im = 0; im < 4; ++im) {
#pragma unroll
        for (int r = 0; r < 4; ++r) {
            int trow = t0 + wm * 64 + im * 16 + quad * 4 + r;
            float rs = 0.f;
#pragma unroll
            for (int jn = 0; jn < 4; ++jn) {
                int s = s0 + wn * 64 + jn * 16 + l15;
                float val = acc[im][jn][r];
                if (s > trow) val = 0.f;
                rs += val;
                Cs[(wm * 64 + im * 16 + quad * 4 + r) * CPITCH + wn * 64 + jn * 16 + l15] = f2b(val);
            }
#pragma unroll
            for (int m = 1; m < 16; m <<= 1) rs += __shfl_xor(rs, m, 64);
            if (l15 == 0) atomicAdd(denom + (b << 12) + trow, rs);
        }
    }
    __syncthreads();
    int r = tid >> 1, ch = (tid & 1) * 64;
    size_t rowo = ((size_t)(b * TSEQ + t0 + r) << 12) + s0 + ch;
#pragma unroll
    for (int i = 0; i < 8; ++i)
        *(u16x8*)(scores + rowo + i * 8) = *(const u16x8*)(Cs + r * CPITCH + ch + i * 8);
}

// ---------------- num = scores @ v (causal K bound), divide by denom ----------------
// ti reversed: longest blocks (most K-iters) dispatch first.
__global__ __launch_bounds__(256) void k_num(
    const u16* __restrict__ scores, const u16* __restrict__ vT,
    const float* __restrict__ denom, float* __restrict__ out) {
    int ji = blockIdx.x, ti = 31 - blockIdx.y, b = blockIdx.z;
    __shared__ __align__(16) u16 As[128 * 64];
    __shared__ __align__(16) u16 Bs[128 * 64];
    int tid = threadIdx.x;
    const u16* A = scores + ((size_t)b << 24);  // [T][T]
    const u16* Bm = vT + ((size_t)b << 22);     // [D][T]
    int t0 = ti * 128, j0 = ji * 128;
    int wid = tid >> 6, lane = tid & 63;
    int wm = wid >> 1, wn = wid & 1, quad = lane >> 4, l15 = lane & 15;
    f32x4 acc[4][4] = {};
    int kmax = (ti + 1) * 128;
    for (int k0 = 0; k0 < kmax; k0 += 64) {
        stage_async(As, A, t0, k0, TSEQ, wid, lane);
        stage_async(Bs, Bm, j0, k0, TSEQ, wid, lane);
        __syncthreads();
        mma_tile(As, Bs, acc, wm, wn, quad, l15);
        __syncthreads();
    }
#pragma unroll
    for (int im = 0; im < 4; ++im) {
#pragma unroll
        for (int r = 0; r < 4; ++r) {
            int t = t0 + wm * 64 + im * 16 + quad * 4 + r;
            float den = denom[(b << 12) + t] + EPSV;
#pragma unroll
            for (int jn = 0; jn < 4; ++jn) {
                int j = j0 + wn * 64 + jn * 16 + l15;
                out[((size_t)(b * TSEQ + t) << 10) + j] = acc[im][jn][r] / den;
            }
        }
    }
}

// ---------------- workspace layout (bytes) ----------------
static const size_t OFF_Q      = 0;
static const size_t OFF_WK     = 33554432;
static const size_t OFF_VT     = 67108864;
static const size_t OFF_DENOM  = 100663296;
static const size_t OFF_BCAT   = 100728832;
static const size_t OFF_XW     = 100745216;
static const size_t OFF_WCAT   = 134299648;
static const size_t OFF_GA     = 176242688;   // now f16: 33.5 MB
static const size_t OFF_PART   = 243351552;
static const size_t OFF_SCORES = OFF_XW;  // 134,217,728 B, overlays dead early region

extern "C" void kernel_launch(void* const* d_in, const int* in_sizes, int n_in,
                              void* d_out, int out_size, void* d_ws, size_t ws_size,
                              hipStream_t stream) {
    const float* x  = (const float*)d_in[0];
    const float* Wq = (const float*)d_in[1];
    const float* bq = (const float*)d_in[2];
    const float* Wk = (const float*)d_in[3];
    const float* bk = (const float*)d_in[4];
    const float* Wv = (const float*)d_in[5];
    const float* bv = (const float*)d_in[6];
    const float* Wa = (const float*)d_in[7];
    const float* ba = (const float*)d_in[8];
    float* out = (float*)d_out;

    char* W = (char*)d_ws;
    u16* qb      = (u16*)(W + OFF_Q);
    u16* wkb     = (u16*)(W + OFF_WK);
    u16* vT      = (u16*)(W + OFF_VT);
    float* denom = (float*)(W + OFF_DENOM);
    float* bcat  = (float*)(W + OFF_BCAT);
    u16* xw      = (u16*)(W + OFF_XW);
    u16* wcat    = (u16*)(W + OFF_WCAT);
    u16* gA      = (u16*)(W + OFF_GA);
    float* part  = (float*)(W + OFF_PART);
    u16* scores  = (u16*)(W + OFF_SCORES);

    k_prep<<<1282, 256, 0, stream>>>(x, Wq, Wk, Wv, Wa, bq, bk, bv, ba, xw, wcat, bcat, denom);

    k_gemm_qkva<<<dim3(32, 128), 256, 0, stream>>>(xw, wcat, bcat, qb, wkb, vT, gA, part);

    k_scan_apply<<<dim3(64, NB, 4), 256, 0, stream>>>(gA, part, wkb);

    k_scores<<<dim3(528, NB), 256, 0, stream>>>(qb, wkb, scores, denom);

    k_num<<<dim3(8, 32, NB), 256, 0, stream>>>(scores, vT, denom, out);
}

// Round 9
// 609.386 us; speedup vs baseline: 1.5179x; 1.0283x over previous
//
#include <hip/hip_runtime.h>

typedef unsigned short u16;
typedef unsigned int u32;

typedef __bf16 bf16x8 __attribute__((ext_vector_type(8)));
typedef float f32x4 __attribute__((ext_vector_type(4)));
typedef u16 u16x8 __attribute__((ext_vector_type(8)));

#define TSEQ 4096
#define DDIM 1024
#define NB 4
#define EPSV 1e-6f
// bounce-buffer row pitch in u16 (272 B = 17*16 -> rows stay 16B-aligned, banks rotate)
#define CPITCH 136

__device__ __forceinline__ u16 f2b(float f) {
    union { float f; u32 u; } v; v.f = f;
    u32 r = v.u + 0x7FFFu + ((v.u >> 16) & 1u);
    return (u16)(r >> 16);
}
__device__ __forceinline__ float b2f(u16 h) {
    union { u32 u; float f; } v; v.u = ((u32)h) << 16; return v.f;
}
__device__ __forceinline__ u16 f2h(float f) {
    union { _Float16 h; u16 u; } v; v.h = (_Float16)f; return v.u;
}
__device__ __forceinline__ float h2f(u16 u) {
    union { u16 u; _Float16 h; } v; v.u = u; return (float)v.h;
}

// ---------------- merged prep: x->bf16, W->bf16 concat, bias concat, denom zero ----
__global__ __launch_bounds__(256) void k_prep(
    const float* __restrict__ x,
    const float* __restrict__ wq, const float* __restrict__ wk,
    const float* __restrict__ wv, const float* __restrict__ wa,
    const float* __restrict__ bq, const float* __restrict__ bk,
    const float* __restrict__ bv, const float* __restrict__ ba,
    u16* __restrict__ xw, u16* __restrict__ wcat, float* __restrict__ bcat,
    float* __restrict__ denom) {
    int bid = blockIdx.x, tid = threadIdx.x;
    if (bid < 1024) {
        // x: 4.19M float4, 1024 blocks x 256 thr x 16
        size_t base = (size_t)bid * 4096 + tid;
#pragma unroll
        for (int k = 0; k < 16; ++k) {
            size_t f4 = base + k * 256;
            float4 f = ((const float4*)x)[f4];
            ushort4 u;
            u.x = f2b(f.x); u.y = f2b(f.y); u.z = f2b(f.z); u.w = f2b(f.w);
            *(ushort4*)(xw + f4 * 4) = u;
        }
    } else if (bid < 1280) {
        // W: 1.05M float4, 256 blocks x 256 thr x 16; each W is 262144 float4
        size_t base = (size_t)(bid - 1024) * 4096 + tid;
#pragma unroll
        for (int k = 0; k < 16; ++k) {
            size_t f4 = base + k * 256;
            int sel = (int)(f4 >> 18);
            const float* src = (sel == 0) ? wq : (sel == 1) ? wk : (sel == 2) ? wv : wa;
            float4 f = ((const float4*)src)[f4 & 262143];
            ushort4 u;
            u.x = f2b(f.x); u.y = f2b(f.y); u.z = f2b(f.z); u.w = f2b(f.w);
            *(ushort4*)(wcat + f4 * 4) = u;
        }
    } else if (bid == 1280) {
#pragma unroll
        for (int c = 0; c < 16; ++c) {
            int j = c * 256 + tid;
            int sel = j >> 10;
            const float* src = (sel == 0) ? bq : (sel == 1) ? bk : (sel == 2) ? bv : ba;
            bcat[j] = src[j & 1023];
        }
    } else {
        // denom zero: NB*TSEQ = 16384 floats = 4096 float4
        float4 z = {0.f, 0.f, 0.f, 0.f};
#pragma unroll
        for (int k = 0; k < 16; ++k)
            ((float4*)denom)[k * 256 + tid] = z;
    }
}

// ---------------- GEMM core helpers ----------------
// Async-stage a 128x64 bf16 tile into LDS with XOR bank swizzle (see round 3).
__device__ __forceinline__ void stage_async(u16* __restrict__ dst, const u16* __restrict__ src,
                                            int row0, int k0, int ld, int wid, int lane) {
#pragma unroll
    for (int c = 0; c < 4; ++c) {
        int rbase = wid * 32 + c * 8;
        int r = rbase + (lane >> 3);
        int hs = (lane & 7) ^ (r & 7);      // swizzled source granule
        const char* g = (const char*)src + ((size_t)(row0 + r) * ld + k0) * 2 + hs * 16;
        char* l = (char*)dst + rbase * 128 + lane * 16;
        __builtin_amdgcn_global_load_lds((const __attribute__((address_space(1))) u32*)g,
                                         (__attribute__((address_space(3))) u32*)l, 16, 0, 0);
    }
}

// One BK=64 MFMA step; un-swizzles fragment reads.
__device__ __forceinline__ void mma_tile(const u16* __restrict__ As, const u16* __restrict__ Bs,
                                         f32x4 acc[4][4], int wm, int wn, int quad, int l15) {
#pragma unroll
    for (int kk = 0; kk < 64; kk += 32) {
        int cg = (kk >> 3) + quad;
        bf16x8 a[4], b[4];
#pragma unroll
        for (int i = 0; i < 4; ++i) {
            int arow = wm * 64 + i * 16 + l15;
            int brow = wn * 64 + i * 16 + l15;
            a[i] = *(const bf16x8*)(As + arow * 64 + ((cg ^ (arow & 7)) << 3));
            b[i] = *(const bf16x8*)(Bs + brow * 64 + ((cg ^ (brow & 7)) << 3));
        }
#pragma unroll
        for (int i = 0; i < 4; ++i)
#pragma unroll
            for (int j = 0; j < 4; ++j)
                acc[i][j] = __builtin_amdgcn_mfma_f32_16x16x32_bf16(a[i], b[j], acc[i][j], 0, 0, 0);
    }
}

// ---------------- fused QKVA projection GEMM ----------------
// n-tile -> output is block-uniform: x 0-7 q, 8-15 k, 16-23 v (written transposed
// into vT), 24-31 gA (f16 log-sigmoid, direct stores) + fused per-chunk partials.
// NOTE: epilogue control flow deliberately matches round 7 (two top-level branches,
// no shared tail) — the round-8 unified-tail variant dropped VGPR 108->92 and
// regressed the K-loop schedule (227->246 us at identical FETCH).
__global__ __launch_bounds__(256) void k_gemm_qkva(
    const u16* __restrict__ xw, const u16* __restrict__ wcat, const float* __restrict__ bcat,
    u16* __restrict__ qb, u16* __restrict__ kb, u16* __restrict__ vT, u16* __restrict__ gA,
    float* __restrict__ part) {
    __shared__ __align__(16) char smem[CPITCH * 128 * 2];  // staging (32KB) U bounce (34KB)
    u16* As = (u16*)smem;
    u16* Bs = (u16*)(smem + 16384);
    int tid = threadIdx.x;
    int m0 = blockIdx.y * 128, n0 = blockIdx.x * 128;
    int wid = tid >> 6, lane = tid & 63;
    int wm = wid >> 1, wn = wid & 1, quad = lane >> 4, l15 = lane & 15;
    f32x4 acc[4][4] = {};
    for (int k0 = 0; k0 < DDIM; k0 += 64) {
        stage_async(As, xw, m0, k0, DDIM, wid, lane);
        stage_async(Bs, wcat, n0, k0, DDIM, wid, lane);
        __syncthreads();
        mma_tile(As, Bs, acc, wm, wn, quad, l15);
        __syncthreads();
    }
    int blk = n0 >> 10, nf0 = n0 & 1023;
    if (blk < 3) {
        // bf16 outputs: bounce through LDS, store vectorized.
        u16* Cs = (u16*)smem;
#pragma unroll
        for (int im = 0; im < 4; ++im)
#pragma unroll
        for (int jn = 0; jn < 4; ++jn) {
            float bias = bcat[n0 + wn * 64 + jn * 16 + l15];
#pragma unroll
            for (int r = 0; r < 4; ++r) {
                float z = acc[im][jn][r] + bias;
                if (blk < 2) z = fmaxf(z, 0.f);
                Cs[(wm * 64 + im * 16 + quad * 4 + r) * CPITCH + wn * 64 + jn * 16 + l15] = f2b(z);
            }
        }
        __syncthreads();
        if (blk < 2) {
            u16* dst = (blk == 0) ? qb : kb;
            int r = tid >> 1, ch = (tid & 1) * 64;
            size_t rowo = (size_t)(m0 + r) * DDIM + nf0 + ch;
#pragma unroll
            for (int i = 0; i < 8; ++i)
                *(u16x8*)(dst + rowo + i * 8) = *(const u16x8*)(Cs + r * CPITCH + ch + i * 8);
        } else {
            // v: read bounce transposed, write vT[b][j][t] coalesced.
            int j = tid >> 1, th = (tid & 1) * 64;
            int bB = m0 >> 12, t0m = m0 & 4095;
            size_t rowo = (((size_t)(bB * DDIM + nf0 + j)) << 12) + t0m + th;
#pragma unroll
            for (int i = 0; i < 8; ++i) {
                u16x8 vv;
#pragma unroll
                for (int e = 0; e < 8; ++e)
                    vv[e] = Cs[(th + i * 8 + e) * CPITCH + j];
                *(u16x8*)(vT + rowo + i * 8) = vv;
            }
        }
    } else {
        // gA: f16 direct stores + fused per-chunk (64-row) column sums.
        int bB = m0 >> 12;
        int cbase = (m0 & 4095) >> 6;  // even; chunk = cbase + wm
#pragma unroll
        for (int jn = 0; jn < 4; ++jn) {
            int n = n0 + wn * 64 + jn * 16 + l15;
            float bias = bcat[n];
            int nf = n & 1023;
            float csum = 0.f;
#pragma unroll
            for (int im = 0; im < 4; ++im)
#pragma unroll
            for (int r = 0; r < 4; ++r) {
                int m = m0 + wm * 64 + im * 16 + quad * 4 + r;
                float z = acc[im][jn][r] + bias;
                float g = __logf(1.f / (1.f + __expf(-z)) + 1e-6f);
                gA[(size_t)m * DDIM + nf] = f2h(g);
                csum += g;
            }
            csum += __shfl_xor(csum, 16, 64);
            csum += __shfl_xor(csum, 32, 64);
            if (quad == 0)
                part[((size_t)(bB * 64 + cbase + wm) << 10) + nf] = csum;
        }
    }
}

// ---------------- gate scan apply (fused suffix-sum of raw chunk partials) ----------------
// One column per thread; grid (chunk, b, colchunk) = 1024 blocks -> 4 blocks/CU.
__global__ __launch_bounds__(256) void k_scan_apply(
    const u16* __restrict__ gA, const float* __restrict__ part, u16* __restrict__ kb) {
    int c = blockIdx.x, b = blockIdx.y;
    int col = blockIdx.z * 256 + threadIdx.x;
    float r = 0.f;
    for (int c2 = c + 1; c2 < 64; ++c2)
        r += part[((size_t)(b * 64 + c2) << 10) + col];
    size_t base = (((size_t)(b * TSEQ + c * 64)) << 10) + col;
#pragma unroll 4
    for (int s = 63; s >= 0; --s) {
        size_t ro = base + ((size_t)s << 10);
        r += h2f(gA[ro]);
        kb[ro] = f2b(b2f(kb[ro]) * __expf(r));
    }
}

// ---------------- scores = q @ wk^T (causal), bf16 out + denom atomics ----------------
// Triangular 1D grid: 528 blocks per batch, si fastest (L2 locality on q A-tile).
__global__ __launch_bounds__(256) void k_scores(
    const u16* __restrict__ qb, const u16* __restrict__ wkb,
    u16* __restrict__ scores, float* __restrict__ denom) {
    int li = blockIdx.x, b = blockIdx.y;
    int ti = (int)((sqrtf(8.f * li + 1.f) - 1.f) * 0.5f);
    while ((ti + 1) * (ti + 2) / 2 <= li) ++ti;
    while (ti * (ti + 1) / 2 > li) --ti;
    int si = li - ti * (ti + 1) / 2;
    __shared__ __align__(16) char smem[CPITCH * 128 * 2];
    u16* As = (u16*)smem;
    u16* Bs = (u16*)(smem + 16384);
    int tid = threadIdx.x;
    const u16* A = qb + ((size_t)b << 22);
    const u16* Bm = wkb + ((size_t)b << 22);
    int t0 = ti * 128, s0 = si * 128;
    int wid = tid >> 6, lane = tid & 63;
    int wm = wid >> 1, wn = wid & 1, quad = lane >> 4, l15 = lane & 15;
    f32x4 acc[4][4] = {};
    for (int k0 = 0; k0 < DDIM; k0 += 64) {
        stage_async(As, A, t0, k0, DDIM, wid, lane);
        stage_async(Bs, Bm, s0, k0, DDIM, wid, lane);
        __syncthreads();
        mma_tile(As, Bs, acc, wm, wn, quad, l15);
        __syncthreads();
    }
    u16* Cs = (u16*)smem;
#pragma unroll
    for (int im = 0; im < 4; ++im) {
#pragma unroll
        for (int r = 0; r < 4; ++r) {
            int trow = t0 + wm * 64 + im * 16 + quad * 4 + r;
            float rs = 0.f;
#pragma unroll
            for (int jn = 0; jn < 4; ++jn) {
                int s = s0 + wn * 64 + jn * 16 + l15;
                float val = acc[im][jn][r];
                if (s > trow) val = 0.f;
                rs += val;
                Cs[(wm * 64 + im * 16 + quad * 4 + r) * CPITCH + wn * 64 + jn * 16 + l15] = f2b(val);
            }
#pragma unroll
            for (int m = 1; m < 16; m <<= 1) rs += __shfl_xor(rs, m, 64);
            if (l15 == 0) atomicAdd(denom + (b << 12) + trow, rs);
        }
    }
    __syncthreads();
    int r = tid >> 1, ch = (tid & 1) * 64;
    size_t rowo = ((size_t)(b * TSEQ + t0 + r) << 12) + s0 + ch;
#pragma unroll
    for (int i = 0; i < 8; ++i)
        *(u16x8*)(scores + rowo + i * 8) = *(const u16x8*)(Cs + r * CPITCH + ch + i * 8);
}

// ---------------- num = scores @ v (causal K bound), divide by denom ----------------
// ti reversed: longest blocks (most K-iters) dispatch first.
__global__ __launch_bounds__(256) void k_num(
    const u16* __restrict__ scores, const u16* __restrict__ vT,
    const float* __restrict__ denom, float* __restrict__ out) {
    int ji = blockIdx.x, ti = 31 - blockIdx.y, b = blockIdx.z;
    __shared__ __align__(16) u16 As[128 * 64];
    __shared__ __align__(16) u16 Bs[128 * 64];
    int tid = threadIdx.x;
    const u16* A = scores + ((size_t)b << 24);  // [T][T]
    const u16* Bm = vT + ((size_t)b << 22);     // [D][T]
    int t0 = ti * 128, j0 = ji * 128;
    int wid = tid >> 6, lane = tid & 63;
    int wm = wid >> 1, wn = wid & 1, quad = lane >> 4, l15 = lane & 15;
    f32x4 acc[4][4] = {};
    int kmax = (ti + 1) * 128;
    for (int k0 = 0; k0 < kmax; k0 += 64) {
        stage_async(As, A, t0, k0, TSEQ, wid, lane);
        stage_async(Bs, Bm, j0, k0, TSEQ, wid, lane);
        __syncthreads();
        mma_tile(As, Bs, acc, wm, wn, quad, l15);
        __syncthreads();
    }
#pragma unroll
    for (int im = 0; im < 4; ++im) {
#pragma unroll
        for (int r = 0; r < 4; ++r) {
            int t = t0 + wm * 64 + im * 16 + quad * 4 + r;
            float den = denom[(b << 12) + t] + EPSV;
#pragma unroll
            for (int jn = 0; jn < 4; ++jn) {
                int j = j0 + wn * 64 + jn * 16 + l15;
                out[((size_t)(b * TSEQ + t) << 10) + j] = acc[im][jn][r] / den;
            }
        }
    }
}

// ---------------- workspace layout (bytes) ----------------
static const size_t OFF_Q      = 0;
static const size_t OFF_WK     = 33554432;
static const size_t OFF_VT     = 67108864;
static const size_t OFF_DENOM  = 100663296;
static const size_t OFF_BCAT   = 100728832;
static const size_t OFF_XW     = 100745216;
static const size_t OFF_WCAT   = 134299648;
static const size_t OFF_GA     = 176242688;   // f16: 33.5 MB
static const size_t OFF_PART   = 243351552;
static const size_t OFF_SCORES = OFF_XW;  // 134,217,728 B, overlays dead early region

extern "C" void kernel_launch(void* const* d_in, const int* in_sizes, int n_in,
                              void* d_out, int out_size, void* d_ws, size_t ws_size,
                              hipStream_t stream) {
    const float* x  = (const float*)d_in[0];
    const float* Wq = (const float*)d_in[1];
    const float* bq = (const float*)d_in[2];
    const float* Wk = (const float*)d_in[3];
    const float* bk = (const float*)d_in[4];
    const float* Wv = (const float*)d_in[5];
    const float* bv = (const float*)d_in[6];
    const float* Wa = (const float*)d_in[7];
    const float* ba = (const float*)d_in[8];
    float* out = (float*)d_out;

    char* W = (char*)d_ws;
    u16* qb      = (u16*)(W + OFF_Q);
    u16* wkb     = (u16*)(W + OFF_WK);
    u16* vT      = (u16*)(W + OFF_VT);
    float* denom = (float*)(W + OFF_DENOM);
    float* bcat  = (float*)(W + OFF_BCAT);
    u16* xw      = (u16*)(W + OFF_XW);
    u16* wcat    = (u16*)(W + OFF_WCAT);
    u16* gA      = (u16*)(W + OFF_GA);
    float* part  = (float*)(W + OFF_PART);
    u16* scores  = (u16*)(W + OFF_SCORES);

    k_prep<<<1282, 256, 0, stream>>>(x, Wq, Wk, Wv, Wa, bq, bk, bv, ba, xw, wcat, bcat, denom);

    k_gemm_qkva<<<dim3(32, 128), 256, 0, stream>>>(xw, wcat, bcat, qb, wkb, vT, gA, part);

    k_scan_apply<<<dim3(64, NB, 4), 256, 0, stream>>>(gA, part, wkb);

    k_scores<<<dim3(528, NB), 256, 0, stream>>>(qb, wkb, scores, denom);

    k_num<<<dim3(8, 32, NB), 256, 0, stream>>>(scores, vT, denom, out);
}

// Round 10
// 560.179 us; speedup vs baseline: 1.6512x; 1.0878x over previous
//
#include <hip/hip_runtime.h>

typedef unsigned short u16;
typedef unsigned int u32;

typedef __bf16 bf16x8 __attribute__((ext_vector_type(8)));
typedef float f32x4 __attribute__((ext_vector_type(4)));
typedef u16 u16x8 __attribute__((ext_vector_type(8)));

#define TSEQ 4096
#define DDIM 1024
#define NB 4
#define EPSV 1e-6f
// bounce-buffer row pitch in u16 (272 B = 17*16 -> rows stay 16B-aligned, banks rotate)
#define CPITCH 136

__device__ __forceinline__ u16 f2b(float f) {
    union { float f; u32 u; } v; v.f = f;
    u32 r = v.u + 0x7FFFu + ((v.u >> 16) & 1u);
    return (u16)(r >> 16);
}
__device__ __forceinline__ float b2f(u16 h) {
    union { u32 u; float f; } v; v.u = ((u32)h) << 16; return v.f;
}
__device__ __forceinline__ u16 f2h(float f) {
    union { _Float16 h; u16 u; } v; v.h = (_Float16)f; return v.u;
}
__device__ __forceinline__ float h2f(u16 u) {
    union { u16 u; _Float16 h; } v; v.u = u; return (float)v.h;
}

// ---------------- merged prep: x->bf16, W->bf16 concat, bias concat, denom zero ----
__global__ __launch_bounds__(256) void k_prep(
    const float* __restrict__ x,
    const float* __restrict__ wq, const float* __restrict__ wk,
    const float* __restrict__ wv, const float* __restrict__ wa,
    const float* __restrict__ bq, const float* __restrict__ bk,
    const float* __restrict__ bv, const float* __restrict__ ba,
    u16* __restrict__ xw, u16* __restrict__ wcat, float* __restrict__ bcat,
    float* __restrict__ denom) {
    int bid = blockIdx.x, tid = threadIdx.x;
    if (bid < 1024) {
        size_t base = (size_t)bid * 4096 + tid;
#pragma unroll
        for (int k = 0; k < 16; ++k) {
            size_t f4 = base + k * 256;
            float4 f = ((const float4*)x)[f4];
            ushort4 u;
            u.x = f2b(f.x); u.y = f2b(f.y); u.z = f2b(f.z); u.w = f2b(f.w);
            *(ushort4*)(xw + f4 * 4) = u;
        }
    } else if (bid < 1280) {
        size_t base = (size_t)(bid - 1024) * 4096 + tid;
#pragma unroll
        for (int k = 0; k < 16; ++k) {
            size_t f4 = base + k * 256;
            int sel = (int)(f4 >> 18);
            const float* src = (sel == 0) ? wq : (sel == 1) ? wk : (sel == 2) ? wv : wa;
            float4 f = ((const float4*)src)[f4 & 262143];
            ushort4 u;
            u.x = f2b(f.x); u.y = f2b(f.y); u.z = f2b(f.z); u.w = f2b(f.w);
            *(ushort4*)(wcat + f4 * 4) = u;
        }
    } else if (bid == 1280) {
#pragma unroll
        for (int c = 0; c < 16; ++c) {
            int j = c * 256 + tid;
            int sel = j >> 10;
            const float* src = (sel == 0) ? bq : (sel == 1) ? bk : (sel == 2) ? bv : ba;
            bcat[j] = src[j & 1023];
        }
    } else {
        float4 z = {0.f, 0.f, 0.f, 0.f};
#pragma unroll
        for (int k = 0; k < 16; ++k)
            ((float4*)denom)[k * 256 + tid] = z;
    }
}

// ---------------- GEMM core helpers ----------------
// Strength-reduced async staging (round 10): the per-lane global base pointer is
// computed ONCE per kernel (the XOR swizzle granule (lane&7)^(r&7) simplifies to
// the k-invariant (lane&7)^(lane>>3) because row chunks are multiples of 8).
// Per k-step only a compile-time byte offset changes -> folds into the
// instruction's 13-bit immediate; zero per-iter address VALU. (m98 disasm showed
// LLVM emitting 21 v_lshl_add_u64 per body for the old recompute-every-iter form;
// VALUBusy 43% was the binding pipe.)
//
// base = src_bytes + (row0 + wid*32 + (lane>>3)) * ld2 + ((lane&7)^(lane>>3))*16
__device__ __forceinline__ void stage_k(u16* __restrict__ dst, const char* __restrict__ base,
                                        int ld2, int kbyte, int wid, int lane) {
#pragma unroll
    for (int c = 0; c < 4; ++c) {
        const char* g = base + c * 8 * ld2 + kbyte;
        char* l = (char*)dst + (wid * 32 + c * 8) * 128 + lane * 16;
        __builtin_amdgcn_global_load_lds((const __attribute__((address_space(1))) u32*)g,
                                         (__attribute__((address_space(3))) u32*)l, 16, 0, 0);
    }
}

// One BK=64 MFMA step; un-swizzles fragment reads (addresses k0-invariant, hoisted).
__device__ __forceinline__ void mma_tile(const u16* __restrict__ As, const u16* __restrict__ Bs,
                                         f32x4 acc[4][4], int wm, int wn, int quad, int l15) {
#pragma unroll
    for (int kk = 0; kk < 64; kk += 32) {
        int cg = (kk >> 3) + quad;
        bf16x8 a[4], b[4];
#pragma unroll
        for (int i = 0; i < 4; ++i) {
            int arow = wm * 64 + i * 16 + l15;
            int brow = wn * 64 + i * 16 + l15;
            a[i] = *(const bf16x8*)(As + arow * 64 + ((cg ^ (arow & 7)) << 3));
            b[i] = *(const bf16x8*)(Bs + brow * 64 + ((cg ^ (brow & 7)) << 3));
        }
#pragma unroll
        for (int i = 0; i < 4; ++i)
#pragma unroll
            for (int j = 0; j < 4; ++j)
                acc[i][j] = __builtin_amdgcn_mfma_f32_16x16x32_bf16(a[i], b[j], acc[i][j], 0, 0, 0);
    }
}

// ---------------- fused QKVA projection GEMM ----------------
// Epilogue control flow deliberately matches round 7/9 (schedule-fragile; see R8).
__global__ __launch_bounds__(256) void k_gemm_qkva(
    const u16* __restrict__ xw, const u16* __restrict__ wcat, const float* __restrict__ bcat,
    u16* __restrict__ qb, u16* __restrict__ kb, u16* __restrict__ vT, u16* __restrict__ gA,
    float* __restrict__ part) {
    __shared__ __align__(16) char smem[CPITCH * 128 * 2];  // staging (32KB) U bounce (34KB)
    u16* As = (u16*)smem;
    u16* Bs = (u16*)(smem + 16384);
    int tid = threadIdx.x;
    int m0 = blockIdx.y * 128, n0 = blockIdx.x * 128;
    int wid = tid >> 6, lane = tid & 63;
    int wm = wid >> 1, wn = wid & 1, quad = lane >> 4, l15 = lane & 15;
    int hxor = (lane & 7) ^ (lane >> 3);
    const char* baA = (const char*)xw + (size_t)(m0 + wid * 32 + (lane >> 3)) * 2048 + hxor * 16;
    const char* baB = (const char*)wcat + (size_t)(n0 + wid * 32 + (lane >> 3)) * 2048 + hxor * 16;
    f32x4 acc[4][4] = {};
#pragma unroll
    for (int k0 = 0; k0 < DDIM; k0 += 64) {
        stage_k(As, baA, 2048, k0 * 2, wid, lane);
        stage_k(Bs, baB, 2048, k0 * 2, wid, lane);
        __syncthreads();
        mma_tile(As, Bs, acc, wm, wn, quad, l15);
        __syncthreads();
    }
    int blk = n0 >> 10, nf0 = n0 & 1023;
    if (blk < 3) {
        // bf16 outputs: bounce through LDS, store vectorized.
        u16* Cs = (u16*)smem;
#pragma unroll
        for (int im = 0; im < 4; ++im)
#pragma unroll
        for (int jn = 0; jn < 4; ++jn) {
            float bias = bcat[n0 + wn * 64 + jn * 16 + l15];
#pragma unroll
            for (int r = 0; r < 4; ++r) {
                float z = acc[im][jn][r] + bias;
                if (blk < 2) z = fmaxf(z, 0.f);
                Cs[(wm * 64 + im * 16 + quad * 4 + r) * CPITCH + wn * 64 + jn * 16 + l15] = f2b(z);
            }
        }
        __syncthreads();
        if (blk < 2) {
            u16* dst = (blk == 0) ? qb : kb;
            int r = tid >> 1, ch = (tid & 1) * 64;
            size_t rowo = (size_t)(m0 + r) * DDIM + nf0 + ch;
#pragma unroll
            for (int i = 0; i < 8; ++i)
                *(u16x8*)(dst + rowo + i * 8) = *(const u16x8*)(Cs + r * CPITCH + ch + i * 8);
        } else {
            // v: read bounce transposed, write vT[b][j][t] coalesced.
            int j = tid >> 1, th = (tid & 1) * 64;
            int bB = m0 >> 12, t0m = m0 & 4095;
            size_t rowo = (((size_t)(bB * DDIM + nf0 + j)) << 12) + t0m + th;
#pragma unroll
            for (int i = 0; i < 8; ++i) {
                u16x8 vv;
#pragma unroll
                for (int e = 0; e < 8; ++e)
                    vv[e] = Cs[(th + i * 8 + e) * CPITCH + j];
                *(u16x8*)(vT + rowo + i * 8) = vv;
            }
        }
    } else {
        // gA: f16 direct stores + fused per-chunk (64-row) column sums.
        int bB = m0 >> 12;
        int cbase = (m0 & 4095) >> 6;  // even; chunk = cbase + wm
#pragma unroll
        for (int jn = 0; jn < 4; ++jn) {
            int n = n0 + wn * 64 + jn * 16 + l15;
            float bias = bcat[n];
            int nf = n & 1023;
            float csum = 0.f;
#pragma unroll
            for (int im = 0; im < 4; ++im)
#pragma unroll
            for (int r = 0; r < 4; ++r) {
                int m = m0 + wm * 64 + im * 16 + quad * 4 + r;
                float z = acc[im][jn][r] + bias;
                float g = __logf(1.f / (1.f + __expf(-z)) + 1e-6f);
                gA[(size_t)m * DDIM + nf] = f2h(g);
                csum += g;
            }
            csum += __shfl_xor(csum, 16, 64);
            csum += __shfl_xor(csum, 32, 64);
            if (quad == 0)
                part[((size_t)(bB * 64 + cbase + wm) << 10) + nf] = csum;
        }
    }
}

// ---------------- gate scan apply (fused suffix-sum of raw chunk partials) ----------------
__global__ __launch_bounds__(256) void k_scan_apply(
    const u16* __restrict__ gA, const float* __restrict__ part, u16* __restrict__ kb) {
    int c = blockIdx.x, b = blockIdx.y;
    int col = blockIdx.z * 256 + threadIdx.x;
    float r = 0.f;
    for (int c2 = c + 1; c2 < 64; ++c2)
        r += part[((size_t)(b * 64 + c2) << 10) + col];
    size_t base = (((size_t)(b * TSEQ + c * 64)) << 10) + col;
#pragma unroll 4
    for (int s = 63; s >= 0; --s) {
        size_t ro = base + ((size_t)s << 10);
        r += h2f(gA[ro]);
        kb[ro] = f2b(b2f(kb[ro]) * __expf(r));
    }
}

// ---------------- scores = q @ wk^T (causal), bf16 out + denom atomics ----------------
// Triangular 1D grid: 528 blocks per batch, si fastest (L2 locality on q A-tile).
__global__ __launch_bounds__(256) void k_scores(
    const u16* __restrict__ qb, const u16* __restrict__ wkb,
    u16* __restrict__ scores, float* __restrict__ denom) {
    int li = blockIdx.x, b = blockIdx.y;
    int ti = (int)((sqrtf(8.f * li + 1.f) - 1.f) * 0.5f);
    while ((ti + 1) * (ti + 2) / 2 <= li) ++ti;
    while (ti * (ti + 1) / 2 > li) --ti;
    int si = li - ti * (ti + 1) / 2;
    __shared__ __align__(16) char smem[CPITCH * 128 * 2];
    u16* As = (u16*)smem;
    u16* Bs = (u16*)(smem + 16384);
    int tid = threadIdx.x;
    const u16* A = qb + ((size_t)b << 22);
    const u16* Bm = wkb + ((size_t)b << 22);
    int t0 = ti * 128, s0 = si * 128;
    int wid = tid >> 6, lane = tid & 63;
    int wm = wid >> 1, wn = wid & 1, quad = lane >> 4, l15 = lane & 15;
    int hxor = (lane & 7) ^ (lane >> 3);
    const char* baA = (const char*)A + (size_t)(t0 + wid * 32 + (lane >> 3)) * 2048 + hxor * 16;
    const char* baB = (const char*)Bm + (size_t)(s0 + wid * 32 + (lane >> 3)) * 2048 + hxor * 16;
    f32x4 acc[4][4] = {};
#pragma unroll
    for (int k0 = 0; k0 < DDIM; k0 += 64) {
        stage_k(As, baA, 2048, k0 * 2, wid, lane);
        stage_k(Bs, baB, 2048, k0 * 2, wid, lane);
        __syncthreads();
        mma_tile(As, Bs, acc, wm, wn, quad, l15);
        __syncthreads();
    }
    u16* Cs = (u16*)smem;
#pragma unroll
    for (int im = 0; im < 4; ++im) {
#pragma unroll
        for (int r = 0; r < 4; ++r) {
            int trow = t0 + wm * 64 + im * 16 + quad * 4 + r;
            float rs = 0.f;
#pragma unroll
            for (int jn = 0; jn < 4; ++jn) {
                int s = s0 + wn * 64 + jn * 16 + l15;
                float val = acc[im][jn][r];
                if (s > trow) val = 0.f;
                rs += val;
                Cs[(wm * 64 + im * 16 + quad * 4 + r) * CPITCH + wn * 64 + jn * 16 + l15] = f2b(val);
            }
#pragma unroll
            for (int m = 1; m < 16; m <<= 1) rs += __shfl_xor(rs, m, 64);
            if (l15 == 0) atomicAdd(denom + (b << 12) + trow, rs);
        }
    }
    __syncthreads();
    int r = tid >> 1, ch = (tid & 1) * 64;
    size_t rowo = ((size_t)(b * TSEQ + t0 + r) << 12) + s0 + ch;
#pragma unroll
    for (int i = 0; i < 8; ++i)
        *(u16x8*)(scores + rowo + i * 8) = *(const u16x8*)(Cs + r * CPITCH + ch + i * 8);
}

// ---------------- num = scores @ v (causal K bound), divide by denom ----------------
// ti reversed: longest blocks first. K-loop unrolled by 2 (128 B in imm offset),
// pointer bump once per 128 k-elements.
__global__ __launch_bounds__(256) void k_num(
    const u16* __restrict__ scores, const u16* __restrict__ vT,
    const float* __restrict__ denom, float* __restrict__ out) {
    int ji = blockIdx.x, ti = 31 - blockIdx.y, b = blockIdx.z;
    __shared__ __align__(16) u16 As[128 * 64];
    __shared__ __align__(16) u16 Bs[128 * 64];
    int tid = threadIdx.x;
    const u16* A = scores + ((size_t)b << 24);  // [T][T]
    const u16* Bm = vT + ((size_t)b << 22);     // [D][T]
    int t0 = ti * 128, j0 = ji * 128;
    int wid = tid >> 6, lane = tid & 63;
    int wm = wid >> 1, wn = wid & 1, quad = lane >> 4, l15 = lane & 15;
    int hxor = (lane & 7) ^ (lane >> 3);
    const char* pA = (const char*)A + (size_t)(t0 + wid * 32 + (lane >> 3)) * 8192 + hxor * 16;
    const char* pB = (const char*)Bm + (size_t)(j0 + wid * 32 + (lane >> 3)) * 8192 + hxor * 16;
    f32x4 acc[4][4] = {};
    int kmax = (ti + 1) * 128;  // multiple of 128 -> unroll-by-2 safe
    for (int k0 = 0; k0 < kmax; k0 += 128) {
        stage_k(As, pA, 8192, 0, wid, lane);
        stage_k(Bs, pB, 8192, 0, wid, lane);
        __syncthreads();
        mma_tile(As, Bs, acc, wm, wn, quad, l15);
        __syncthreads();
        stage_k(As, pA, 8192, 128, wid, lane);
        stage_k(Bs, pB, 8192, 128, wid, lane);
        __syncthreads();
        mma_tile(As, Bs, acc, wm, wn, quad, l15);
        __syncthreads();
        pA += 256; pB += 256;
    }
#pragma unroll
    for (int im = 0; im < 4; ++im) {
#pragma unroll
        for (int r = 0; r < 4; ++r) {
            int t = t0 + wm * 64 + im * 16 + quad * 4 + r;
            float den = denom[(b << 12) + t] + EPSV;
#pragma unroll
            for (int jn = 0; jn < 4; ++jn) {
                int j = j0 + wn * 64 + jn * 16 + l15;
                out[((size_t)(b * TSEQ + t) << 10) + j] = acc[im][jn][r] / den;
            }
        }
    }
}

// ---------------- workspace layout (bytes) ----------------
static const size_t OFF_Q      = 0;
static const size_t OFF_WK     = 33554432;
static const size_t OFF_VT     = 67108864;
static const size_t OFF_DENOM  = 100663296;
static const size_t OFF_BCAT   = 100728832;
static const size_t OFF_XW     = 100745216;
static const size_t OFF_WCAT   = 134299648;
static const size_t OFF_GA     = 176242688;   // f16: 33.5 MB
static const size_t OFF_PART   = 243351552;
static const size_t OFF_SCORES = OFF_XW;  // 134,217,728 B, overlays dead early region

extern "C" void kernel_launch(void* const* d_in, const int* in_sizes, int n_in,
                              void* d_out, int out_size, void* d_ws, size_t ws_size,
                              hipStream_t stream) {
    const float* x  = (const float*)d_in[0];
    const float* Wq = (const float*)d_in[1];
    const float* bq = (const float*)d_in[2];
    const float* Wk = (const float*)d_in[3];
    const float* bk = (const float*)d_in[4];
    const float* Wv = (const float*)d_in[5];
    const float* bv = (const float*)d_in[6];
    const float* Wa = (const float*)d_in[7];
    const float* ba = (const float*)d_in[8];
    float* out = (float*)d_out;

    char* W = (char*)d_ws;
    u16* qb      = (u16*)(W + OFF_Q);
    u16* wkb     = (u16*)(W + OFF_WK);
    u16* vT      = (u16*)(W + OFF_VT);
    float* denom = (float*)(W + OFF_DENOM);
    float* bcat  = (float*)(W + OFF_BCAT);
    u16* xw      = (u16*)(W + OFF_XW);
    u16* wcat    = (u16*)(W + OFF_WCAT);
    u16* gA      = (u16*)(W + OFF_GA);
    float* part  = (float*)(W + OFF_PART);
    u16* scores  = (u16*)(W + OFF_SCORES);

    k_prep<<<1282, 256, 0, stream>>>(x, Wq, Wk, Wv, Wa, bq, bk, bv, ba, xw, wcat, bcat, denom);

    k_gemm_qkva<<<dim3(32, 128), 256, 0, stream>>>(xw, wcat, bcat, qb, wkb, vT, gA, part);

    k_scan_apply<<<dim3(64, NB, 4), 256, 0, stream>>>(gA, part, wkb);

    k_scores<<<dim3(528, NB), 256, 0, stream>>>(qb, wkb, scores, denom);

    k_num<<<dim3(8, 32, NB), 256, 0, stream>>>(scores, vT, denom, out);
}

// Round 11
// 548.010 us; speedup vs baseline: 1.6879x; 1.0222x over previous
//
#include <hip/hip_runtime.h>

typedef unsigned short u16;
typedef unsigned int u32;

typedef __bf16 bf16x8 __attribute__((ext_vector_type(8)));
typedef float f32x4 __attribute__((ext_vector_type(4)));
typedef u16 u16x8 __attribute__((ext_vector_type(8)));

#define TSEQ 4096
#define DDIM 1024
#define NB 4
#define EPSV 1e-6f
// bounce-buffer row pitch in u16 (272 B = 17*16 -> rows stay 16B-aligned, banks rotate)
#define CPITCH 136

__device__ __forceinline__ u16 f2b(float f) {
    union { float f; u32 u; } v; v.f = f;
    u32 r = v.u + 0x7FFFu + ((v.u >> 16) & 1u);
    return (u16)(r >> 16);
}
__device__ __forceinline__ float b2f(u16 h) {
    union { u32 u; float f; } v; v.u = ((u32)h) << 16; return v.f;
}
__device__ __forceinline__ u16 f2h(float f) {
    union { _Float16 h; u16 u; } v; v.h = (_Float16)f; return v.u;
}
__device__ __forceinline__ float h2f(u16 u) {
    union { u16 u; _Float16 h; } v; v.u = u; return (float)v.h;
}

// ---------------- merged prep: x->bf16, W->bf16 concat, bias concat, denom zero ----
__global__ __launch_bounds__(256) void k_prep(
    const float* __restrict__ x,
    const float* __restrict__ wq, const float* __restrict__ wk,
    const float* __restrict__ wv, const float* __restrict__ wa,
    const float* __restrict__ bq, const float* __restrict__ bk,
    const float* __restrict__ bv, const float* __restrict__ ba,
    u16* __restrict__ xw, u16* __restrict__ wcat, float* __restrict__ bcat,
    float* __restrict__ denom) {
    int bid = blockIdx.x, tid = threadIdx.x;
    if (bid < 1024) {
        size_t base = (size_t)bid * 4096 + tid;
#pragma unroll
        for (int k = 0; k < 16; ++k) {
            size_t f4 = base + k * 256;
            float4 f = ((const float4*)x)[f4];
            ushort4 u;
            u.x = f2b(f.x); u.y = f2b(f.y); u.z = f2b(f.z); u.w = f2b(f.w);
            *(ushort4*)(xw + f4 * 4) = u;
        }
    } else if (bid < 1280) {
        size_t base = (size_t)(bid - 1024) * 4096 + tid;
#pragma unroll
        for (int k = 0; k < 16; ++k) {
            size_t f4 = base + k * 256;
            int sel = (int)(f4 >> 18);
            const float* src = (sel == 0) ? wq : (sel == 1) ? wk : (sel == 2) ? wv : wa;
            float4 f = ((const float4*)src)[f4 & 262143];
            ushort4 u;
            u.x = f2b(f.x); u.y = f2b(f.y); u.z = f2b(f.z); u.w = f2b(f.w);
            *(ushort4*)(wcat + f4 * 4) = u;
        }
    } else if (bid == 1280) {
#pragma unroll
        for (int c = 0; c < 16; ++c) {
            int j = c * 256 + tid;
            int sel = j >> 10;
            const float* src = (sel == 0) ? bq : (sel == 1) ? bk : (sel == 2) ? bv : ba;
            bcat[j] = src[j & 1023];
        }
    } else {
        float4 z = {0.f, 0.f, 0.f, 0.f};
#pragma unroll
        for (int k = 0; k < 16; ++k)
            ((float4*)denom)[k * 256 + tid] = z;
    }
}

// ---------------- GEMM core helpers ----------------
// Strength-reduced async staging (round 10): per-lane global base pointer computed
// once; per k-step only a compile-time byte offset changes (13-bit immediate).
__device__ __forceinline__ void stage_k(u16* __restrict__ dst, const char* __restrict__ base,
                                        int ld2, int kbyte, int wid, int lane) {
#pragma unroll
    for (int c = 0; c < 4; ++c) {
        const char* g = base + c * 8 * ld2 + kbyte;
        char* l = (char*)dst + (wid * 32 + c * 8) * 128 + lane * 16;
        __builtin_amdgcn_global_load_lds((const __attribute__((address_space(1))) u32*)g,
                                         (__attribute__((address_space(3))) u32*)l, 16, 0, 0);
    }
}

// One BK=64 MFMA step; un-swizzles fragment reads (addresses k0-invariant, hoisted).
__device__ __forceinline__ void mma_tile(const u16* __restrict__ As, const u16* __restrict__ Bs,
                                         f32x4 acc[4][4], int wm, int wn, int quad, int l15) {
#pragma unroll
    for (int kk = 0; kk < 64; kk += 32) {
        int cg = (kk >> 3) + quad;
        bf16x8 a[4], b[4];
#pragma unroll
        for (int i = 0; i < 4; ++i) {
            int arow = wm * 64 + i * 16 + l15;
            int brow = wn * 64 + i * 16 + l15;
            a[i] = *(const bf16x8*)(As + arow * 64 + ((cg ^ (arow & 7)) << 3));
            b[i] = *(const bf16x8*)(Bs + brow * 64 + ((cg ^ (brow & 7)) << 3));
        }
#pragma unroll
        for (int i = 0; i < 4; ++i)
#pragma unroll
            for (int j = 0; j < 4; ++j)
                acc[i][j] = __builtin_amdgcn_mfma_f32_16x16x32_bf16(a[i], b[j], acc[i][j], 0, 0, 0);
    }
}

// ---------------- fused QKVA projection GEMM ----------------
// Round 11: grid is m-FASTEST (grid.x = m-tiles): bid%8 == m%8, so each xw m-tile
// is pinned to one XCD's L2 (fetched once per XCD instead of 8x). Epilogue control
// flow deliberately matches round 7/9 (schedule-fragile; see R8).
__global__ __launch_bounds__(256) void k_gemm_qkva(
    const u16* __restrict__ xw, const u16* __restrict__ wcat, const float* __restrict__ bcat,
    u16* __restrict__ qb, u16* __restrict__ kb, u16* __restrict__ vT, u16* __restrict__ gA,
    float* __restrict__ part) {
    __shared__ __align__(16) char smem[CPITCH * 128 * 2];  // staging (32KB) U bounce (34KB)
    u16* As = (u16*)smem;
    u16* Bs = (u16*)(smem + 16384);
    int tid = threadIdx.x;
    int m0 = blockIdx.x * 128, n0 = blockIdx.y * 128;   // m fastest (XCD pin)
    int wid = tid >> 6, lane = tid & 63;
    int wm = wid >> 1, wn = wid & 1, quad = lane >> 4, l15 = lane & 15;
    int hxor = (lane & 7) ^ (lane >> 3);
    const char* baA = (const char*)xw + (size_t)(m0 + wid * 32 + (lane >> 3)) * 2048 + hxor * 16;
    const char* baB = (const char*)wcat + (size_t)(n0 + wid * 32 + (lane >> 3)) * 2048 + hxor * 16;
    f32x4 acc[4][4] = {};
#pragma unroll
    for (int k0 = 0; k0 < DDIM; k0 += 64) {
        stage_k(As, baA, 2048, k0 * 2, wid, lane);
        stage_k(Bs, baB, 2048, k0 * 2, wid, lane);
        __syncthreads();
        mma_tile(As, Bs, acc, wm, wn, quad, l15);
        __syncthreads();
    }
    int blk = n0 >> 10, nf0 = n0 & 1023;
    if (blk < 3) {
        // bf16 outputs: bounce through LDS, store vectorized.
        u16* Cs = (u16*)smem;
#pragma unroll
        for (int im = 0; im < 4; ++im)
#pragma unroll
        for (int jn = 0; jn < 4; ++jn) {
            float bias = bcat[n0 + wn * 64 + jn * 16 + l15];
#pragma unroll
            for (int r = 0; r < 4; ++r) {
                float z = acc[im][jn][r] + bias;
                if (blk < 2) z = fmaxf(z, 0.f);
                Cs[(wm * 64 + im * 16 + quad * 4 + r) * CPITCH + wn * 64 + jn * 16 + l15] = f2b(z);
            }
        }
        __syncthreads();
        if (blk < 2) {
            u16* dst = (blk == 0) ? qb : kb;
            int r = tid >> 1, ch = (tid & 1) * 64;
            size_t rowo = (size_t)(m0 + r) * DDIM + nf0 + ch;
#pragma unroll
            for (int i = 0; i < 8; ++i)
                *(u16x8*)(dst + rowo + i * 8) = *(const u16x8*)(Cs + r * CPITCH + ch + i * 8);
        } else {
            // v: read bounce transposed, write vT[b][j][t] coalesced.
            int j = tid >> 1, th = (tid & 1) * 64;
            int bB = m0 >> 12, t0m = m0 & 4095;
            size_t rowo = (((size_t)(bB * DDIM + nf0 + j)) << 12) + t0m + th;
#pragma unroll
            for (int i = 0; i < 8; ++i) {
                u16x8 vv;
#pragma unroll
                for (int e = 0; e < 8; ++e)
                    vv[e] = Cs[(th + i * 8 + e) * CPITCH + j];
                *(u16x8*)(vT + rowo + i * 8) = vv;
            }
        }
    } else {
        // gA: f16 direct stores + fused per-chunk (64-row) column sums.
        int bB = m0 >> 12;
        int cbase = (m0 & 4095) >> 6;  // even; chunk = cbase + wm
#pragma unroll
        for (int jn = 0; jn < 4; ++jn) {
            int n = n0 + wn * 64 + jn * 16 + l15;
            float bias = bcat[n];
            int nf = n & 1023;
            float csum = 0.f;
#pragma unroll
            for (int im = 0; im < 4; ++im)
#pragma unroll
            for (int r = 0; r < 4; ++r) {
                int m = m0 + wm * 64 + im * 16 + quad * 4 + r;
                float z = acc[im][jn][r] + bias;
                float g = __logf(1.f / (1.f + __expf(-z)) + 1e-6f);
                gA[(size_t)m * DDIM + nf] = f2h(g);
                csum += g;
            }
            csum += __shfl_xor(csum, 16, 64);
            csum += __shfl_xor(csum, 32, 64);
            if (quad == 0)
                part[((size_t)(bB * 64 + cbase + wm) << 10) + nf] = csum;
        }
    }
}

// ---------------- gate scan apply (fused suffix-sum of raw chunk partials) ----------------
__global__ __launch_bounds__(256) void k_scan_apply(
    const u16* __restrict__ gA, const float* __restrict__ part, u16* __restrict__ kb) {
    int c = blockIdx.x, b = blockIdx.y;
    int col = blockIdx.z * 256 + threadIdx.x;
    float r = 0.f;
    for (int c2 = c + 1; c2 < 64; ++c2)
        r += part[((size_t)(b * 64 + c2) << 10) + col];
    size_t base = (((size_t)(b * TSEQ + c * 64)) << 10) + col;
#pragma unroll 4
    for (int s = 63; s >= 0; --s) {
        size_t ro = base + ((size_t)s << 10);
        r += h2f(gA[ro]);
        kb[ro] = f2b(b2f(kb[ro]) * __expf(r));
    }
}

// ---------------- scores = q @ wk^T (causal), bf16 out + denom atomics ----------------
// Round 11: explicit XCD-balanced mapping. XCD x (= bid%8 heuristic) owns ti rows
// {x, 15-x, 16+x, 31-x} (sum of ti+1 = 66 for every x -> perfectly balanced).
// Within an XCD the sequence is si-major across its rows: the wk si-tile is fetched
// once and reused by up to 4 rows; the 4 q row-tiles (1 MB) stay L2-resident.
__global__ __launch_bounds__(256) void k_scores(
    const u16* __restrict__ qb, const u16* __restrict__ wkb,
    u16* __restrict__ scores, float* __restrict__ denom) {
    int bid = blockIdx.x, b = blockIdx.y;
    int xc = bid & 7, idx = bid >> 3;          // idx in [0, 66)
    int rs0 = xc, rs1 = 15 - xc, rs2 = 16 + xc, rs3 = 31 - xc;  // ascending
    int si = 0, rem = idx;
    for (; si < 32; ++si) {
        int n = (rs0 >= si) + (rs1 >= si) + (rs2 >= si) + (rs3 >= si);
        if (rem < n) break;
        rem -= n;
    }
    int ti = rs3, cnt = 0;
    if (rs0 >= si) { if (cnt == rem) ti = rs0; ++cnt; }
    if (rs1 >= si) { if (cnt == rem) ti = rs1; ++cnt; }
    if (rs2 >= si) { if (cnt == rem) ti = rs2; ++cnt; }
    if (rs3 >= si) { if (cnt == rem) ti = rs3; ++cnt; }
    __shared__ __align__(16) char smem[CPITCH * 128 * 2];
    u16* As = (u16*)smem;
    u16* Bs = (u16*)(smem + 16384);
    int tid = threadIdx.x;
    const u16* A = qb + ((size_t)b << 22);
    const u16* Bm = wkb + ((size_t)b << 22);
    int t0 = ti * 128, s0 = si * 128;
    int wid = tid >> 6, lane = tid & 63;
    int wm = wid >> 1, wn = wid & 1, quad = lane >> 4, l15 = lane & 15;
    int hxor = (lane & 7) ^ (lane >> 3);
    const char* baA = (const char*)A + (size_t)(t0 + wid * 32 + (lane >> 3)) * 2048 + hxor * 16;
    const char* baB = (const char*)Bm + (size_t)(s0 + wid * 32 + (lane >> 3)) * 2048 + hxor * 16;
    f32x4 acc[4][4] = {};
#pragma unroll
    for (int k0 = 0; k0 < DDIM; k0 += 64) {
        stage_k(As, baA, 2048, k0 * 2, wid, lane);
        stage_k(Bs, baB, 2048, k0 * 2, wid, lane);
        __syncthreads();
        mma_tile(As, Bs, acc, wm, wn, quad, l15);
        __syncthreads();
    }
    u16* Cs = (u16*)smem;
#pragma unroll
    for (int im = 0; im < 4; ++im) {
#pragma unroll
        for (int r = 0; r < 4; ++r) {
            int trow = t0 + wm * 64 + im * 16 + quad * 4 + r;
            float rs = 0.f;
#pragma unroll
            for (int jn = 0; jn < 4; ++jn) {
                int s = s0 + wn * 64 + jn * 16 + l15;
                float val = acc[im][jn][r];
                if (s > trow) val = 0.f;
                rs += val;
                Cs[(wm * 64 + im * 16 + quad * 4 + r) * CPITCH + wn * 64 + jn * 16 + l15] = f2b(val);
            }
#pragma unroll
            for (int m = 1; m < 16; m <<= 1) rs += __shfl_xor(rs, m, 64);
            if (l15 == 0) atomicAdd(denom + (b << 12) + trow, rs);
        }
    }
    __syncthreads();
    int r = tid >> 1, ch = (tid & 1) * 64;
    size_t rowo = ((size_t)(b * TSEQ + t0 + r) << 12) + s0 + ch;
#pragma unroll
    for (int i = 0; i < 8; ++i)
        *(u16x8*)(scores + rowo + i * 8) = *(const u16x8*)(Cs + r * CPITCH + ch + i * 8);
}

// ---------------- num = scores @ v (causal K bound), divide by denom ----------------
// ti reversed (longest first). Grid x = ji (8): bid%8 == ji -> vT j-slice naturally
// pinned per XCD (1 MB, L2-resident) -- keep as-is.
__global__ __launch_bounds__(256) void k_num(
    const u16* __restrict__ scores, const u16* __restrict__ vT,
    const float* __restrict__ denom, float* __restrict__ out) {
    int ji = blockIdx.x, ti = 31 - blockIdx.y, b = blockIdx.z;
    __shared__ __align__(16) u16 As[128 * 64];
    __shared__ __align__(16) u16 Bs[128 * 64];
    int tid = threadIdx.x;
    const u16* A = scores + ((size_t)b << 24);  // [T][T]
    const u16* Bm = vT + ((size_t)b << 22);     // [D][T]
    int t0 = ti * 128, j0 = ji * 128;
    int wid = tid >> 6, lane = tid & 63;
    int wm = wid >> 1, wn = wid & 1, quad = lane >> 4, l15 = lane & 15;
    int hxor = (lane & 7) ^ (lane >> 3);
    const char* pA = (const char*)A + (size_t)(t0 + wid * 32 + (lane >> 3)) * 8192 + hxor * 16;
    const char* pB = (const char*)Bm + (size_t)(j0 + wid * 32 + (lane >> 3)) * 8192 + hxor * 16;
    f32x4 acc[4][4] = {};
    int kmax = (ti + 1) * 128;  // multiple of 128 -> unroll-by-2 safe
    for (int k0 = 0; k0 < kmax; k0 += 128) {
        stage_k(As, pA, 8192, 0, wid, lane);
        stage_k(Bs, pB, 8192, 0, wid, lane);
        __syncthreads();
        mma_tile(As, Bs, acc, wm, wn, quad, l15);
        __syncthreads();
        stage_k(As, pA, 8192, 128, wid, lane);
        stage_k(Bs, pB, 8192, 128, wid, lane);
        __syncthreads();
        mma_tile(As, Bs, acc, wm, wn, quad, l15);
        __syncthreads();
        pA += 256; pB += 256;
    }
#pragma unroll
    for (int im = 0; im < 4; ++im) {
#pragma unroll
        for (int r = 0; r < 4; ++r) {
            int t = t0 + wm * 64 + im * 16 + quad * 4 + r;
            float den = denom[(b << 12) + t] + EPSV;
#pragma unroll
            for (int jn = 0; jn < 4; ++jn) {
                int j = j0 + wn * 64 + jn * 16 + l15;
                out[((size_t)(b * TSEQ + t) << 10) + j] = acc[im][jn][r] / den;
            }
        }
    }
}

// ---------------- workspace layout (bytes) ----------------
static const size_t OFF_Q      = 0;
static const size_t OFF_WK     = 33554432;
static const size_t OFF_VT     = 67108864;
static const size_t OFF_DENOM  = 100663296;
static const size_t OFF_BCAT   = 100728832;
static const size_t OFF_XW     = 100745216;
static const size_t OFF_WCAT   = 134299648;
static const size_t OFF_GA     = 176242688;   // f16: 33.5 MB
static const size_t OFF_PART   = 243351552;
static const size_t OFF_SCORES = OFF_XW;  // 134,217,728 B, overlays dead early region

extern "C" void kernel_launch(void* const* d_in, const int* in_sizes, int n_in,
                              void* d_out, int out_size, void* d_ws, size_t ws_size,
                              hipStream_t stream) {
    const float* x  = (const float*)d_in[0];
    const float* Wq = (const float*)d_in[1];
    const float* bq = (const float*)d_in[2];
    const float* Wk = (const float*)d_in[3];
    const float* bk = (const float*)d_in[4];
    const float* Wv = (const float*)d_in[5];
    const float* bv = (const float*)d_in[6];
    const float* Wa = (const float*)d_in[7];
    const float* ba = (const float*)d_in[8];
    float* out = (float*)d_out;

    char* W = (char*)d_ws;
    u16* qb      = (u16*)(W + OFF_Q);
    u16* wkb     = (u16*)(W + OFF_WK);
    u16* vT      = (u16*)(W + OFF_VT);
    float* denom = (float*)(W + OFF_DENOM);
    float* bcat  = (float*)(W + OFF_BCAT);
    u16* xw      = (u16*)(W + OFF_XW);
    u16* wcat    = (u16*)(W + OFF_WCAT);
    u16* gA      = (u16*)(W + OFF_GA);
    float* part  = (float*)(W + OFF_PART);
    u16* scores  = (u16*)(W + OFF_SCORES);

    k_prep<<<1282, 256, 0, stream>>>(x, Wq, Wk, Wv, Wa, bq, bk, bv, ba, xw, wcat, bcat, denom);

    k_gemm_qkva<<<dim3(128, 32), 256, 0, stream>>>(xw, wcat, bcat, qb, wkb, vT, gA, part);

    k_scan_apply<<<dim3(64, NB, 4), 256, 0, stream>>>(gA, part, wkb);

    k_scores<<<dim3(528, NB), 256, 0, stream>>>(qb, wkb, scores, denom);

    k_num<<<dim3(8, 32, NB), 256, 0, stream>>>(scores, vT, denom, out);
}